// Round 10
// baseline (215.430 us; speedup 1.0000x reference)
//
#include <hip/hip_runtime.h>
#include <hip/hip_bf16.h>
#include <stdint.h>

#define NH 16
#define HDIM 64
#define NB 2
#define NSEQ 2048
#define DM 1024
#define MROWS (NB * NSEQ)   // 4096

typedef __attribute__((ext_vector_type(8))) short bf16x8;
typedef __attribute__((ext_vector_type(4))) float f32x4;

#define MFMA32(a, b, c) __builtin_amdgcn_mfma_f32_16x16x32_bf16(a, b, c, 0, 0, 0)

static __device__ __forceinline__ unsigned short f2bf(float f) {
    union { float f; unsigned u; } v;
    v.f = f;
    unsigned r = v.u + 0x7fffu + ((v.u >> 16) & 1u);   // RNE
    return (unsigned short)(r >> 16);
}

static __device__ __forceinline__ unsigned pack2bf(float a, float b) {
#if __has_builtin(__builtin_amdgcn_cvt_pk_bf16_f32)
    typedef __attribute__((ext_vector_type(2))) __bf16 bf2_t;
    union { bf2_t v; unsigned u; } c;
    c.v = __builtin_amdgcn_cvt_pk_bf16_f32(a, b);
    return c.u;
#else
    return (unsigned)f2bf(a) | ((unsigned)f2bf(b) << 16);
#endif
}

static __device__ __forceinline__ float fexp2(float x) {
#if __has_builtin(__builtin_amdgcn_exp2f)
    return __builtin_amdgcn_exp2f(x);
#else
    return exp2f(x);
#endif
}

typedef __attribute__((address_space(1))) void* gas_ptr;
typedef __attribute__((address_space(3))) void* las_ptr;

// async global->LDS, 16B per lane. LDS dest must be wave-uniform base + lane*16.
static __device__ __forceinline__ void load16_lds(const void* g, void* l) {
    __builtin_amdgcn_global_load_lds((gas_ptr)(uintptr_t)g, (las_ptr)(uintptr_t)l,
                                     16, 0, 0);
}

// ---------------------------------------------------------------------------
// Convert: x -> bf16 (blocks 0..1023), weights -> bf16 transposed via LDS
// tile transpose (blocks 1024..2047).
// ---------------------------------------------------------------------------
__global__ __launch_bounds__(256) void convert_kernel(
    const float* __restrict__ x,
    const float* __restrict__ wq, const float* __restrict__ wk,
    const float* __restrict__ wv, const float* __restrict__ wo,
    unsigned short* __restrict__ xb,
    unsigned short* __restrict__ wqkvt,
    unsigned short* __restrict__ wot)
{
    __shared__ unsigned short Ts[64][66];
    int t = threadIdx.x;
    int bx = blockIdx.x;
    if (bx < 1024) {
        const float4* xs = (const float4*)x + (long)bx * 1024;
        unsigned short* xd = xb + (long)bx * 4096;
#pragma unroll
        for (int i = 0; i < 4; i++) {
            float4 v = xs[i * 256 + t];
            ushort4 o;
            o.x = f2bf(v.x); o.y = f2bf(v.y); o.z = f2bf(v.z); o.w = f2bf(v.w);
            *(ushort4*)(xd + (i * 256 + t) * 4) = o;
        }
        return;
    }
    int wi = bx - 1024;
    int wsel = wi >> 8;                 // 0..3 = q,k,v,o
    int tile = wi & 255;
    int k0 = (tile >> 4) * 64, c0 = (tile & 15) * 64;
    const float* w = (wsel == 0) ? wq : (wsel == 1) ? wk : (wsel == 2) ? wv : wo;
    int lr = t >> 6, lc = t & 63;
#pragma unroll
    for (int rr = 0; rr < 16; rr++) {
        int row = rr * 4 + lr;
        Ts[row][lc] = f2bf(w[(long)(k0 + row) * DM + c0 + lc]);
    }
    __syncthreads();
    unsigned short* dst = (wsel == 3) ? wot : (wqkvt + (long)wsel * DM * DM);
#pragma unroll
    for (int rr = 0; rr < 16; rr++) {
        int crow = rr * 4 + lr;
        dst[(long)(c0 + crow) * DM + k0 + lc] = Ts[lc][crow];
    }
}

// ---------------------------------------------------------------------------
// m97-style 128x128 GEMM core (unchanged).
// ---------------------------------------------------------------------------
static __device__ __forceinline__ void gemm_tile_128(
    const unsigned short* __restrict__ A, const unsigned short* __restrict__ Bt,
    int m0, int n0, unsigned short* As, unsigned short* Bs, f32x4 (&acc)[4][4])
{
    int t = threadIdx.x;
    int lane = t & 63;
    int wave = t >> 6;
    int l16 = lane & 15, quad = lane >> 4;
    int wm = wave >> 1, wn = wave & 1;

    int off0 = t * 16;
    int off1 = off0 + 4096;
    const char* ga0 = (const char*)(A + (long)(m0 + (off0 >> 6)) * DM) + (off0 & 63);
    const char* ga1 = (const char*)(A + (long)(m0 + (off1 >> 6)) * DM) + (off1 & 63);
    const char* gb0 = (const char*)(Bt + (long)(n0 + (off0 >> 6)) * DM) + (off0 & 63);
    const char* gb1 = (const char*)(Bt + (long)(n0 + (off1 >> 6)) * DM) + (off1 & 63);
    char* sa0 = (char*)As + off0;
    char* sa1 = (char*)As + off1;
    char* sb0 = (char*)Bs + off0;
    char* sb1 = (char*)Bs + off1;

    const unsigned short* fa = As + (wm * 64 + l16) * 32 + quad * 8;
    const unsigned short* fb = Bs + (wn * 64 + l16) * 32 + quad * 8;

    for (int kk = 0; kk < DM; kk += 32) {
        load16_lds(ga0 + kk * 2, sa0);
        load16_lds(ga1 + kk * 2, sa1);
        load16_lds(gb0 + kk * 2, sb0);
        load16_lds(gb1 + kk * 2, sb1);
        __syncthreads();
        bf16x8 af[4], bf[4];
#pragma unroll
        for (int r = 0; r < 4; r++) af[r] = *(const bf16x8*)(fa + r * 16 * 32);
#pragma unroll
        for (int c = 0; c < 4; c++) bf[c] = *(const bf16x8*)(fb + c * 16 * 32);
#pragma unroll
        for (int r = 0; r < 4; r++)
#pragma unroll
            for (int c = 0; c < 4; c++)
                acc[r][c] = MFMA32(af[r], bf[c], acc[r][c]);
        __syncthreads();
    }
}

// ---------------------------------------------------------------------------
// Fused QKV GEMM (unchanged from round 9).
// ---------------------------------------------------------------------------
__global__ __launch_bounds__(256) void qkv_gemm_kernel(
    const unsigned short* __restrict__ A,
    const unsigned short* __restrict__ Bt,
    unsigned short* __restrict__ Qo, unsigned short* __restrict__ Ko,
    unsigned short* __restrict__ Vt)
{
    __shared__ unsigned short As[128 * 32];
    __shared__ unsigned short Bs[128 * 32];
    __shared__ unsigned short Tw[4][16][72];

    f32x4 acc[4][4] = {};
    int m0 = blockIdx.y * 128, n0 = blockIdx.x * 128;
    gemm_tile_128(A, Bt, m0, n0, As, Bs, acc);

    int t = threadIdx.x, wave = t >> 6, lane = t & 63;
    int l16 = lane & 15, quad = lane >> 4;
    int wm = wave >> 1, wn = wave & 1;
    int rg0 = m0 + wm * 64;
    int cg0 = n0 + wn * 64;
    int z = cg0 >> 10;
    int b_ = rg0 >> 11;
    int nb0 = rg0 & (NSEQ - 1);
    int h = (cg0 & 1023) >> 6;
    long bh = (long)(b_ * NH + h);

    if (z < 2) {
        unsigned short* dst = (z == 0 ? Qo : Ko) + bh * NSEQ * HDIM;
#pragma unroll
        for (int r = 0; r < 4; r++)
#pragma unroll
            for (int reg = 0; reg < 4; reg++) {
                long rowb = (long)(nb0 + r * 16 + quad * 4 + reg) * HDIM;
#pragma unroll
                for (int c = 0; c < 4; c++)
                    dst[rowb + c * 16 + l16] = f2bf(acc[r][c][reg]);
            }
    } else {
        unsigned short* dst = Vt + bh * HDIM * NSEQ;
#pragma unroll
        for (int c = 0; c < 4; c++) {
#pragma unroll
            for (int r = 0; r < 4; r++) {
                ushort4 u;
                u.x = f2bf(acc[r][c][0]); u.y = f2bf(acc[r][c][1]);
                u.z = f2bf(acc[r][c][2]); u.w = f2bf(acc[r][c][3]);
                *(ushort4*)&Tw[wave][l16][r * 16 + quad * 4] = u;   // [hd][n]
            }
#pragma unroll
            for (int j = 0; j < 4; j++) {
                int lrow = j * 4 + quad;
                ushort4 u = *(const ushort4*)&Tw[wave][lrow][l16 * 4];
                *(ushort4*)(dst + (long)(c * 16 + lrow) * NSEQ + nb0 + l16 * 4) = u;
            }
        }
    }
}

// ---------------------------------------------------------------------------
// Flash attention v8: occupancy-doubled. 64 tiles of 32 queries, pair-fused
// (p, 63-p) => 32 pairs x 32 bh = 1024 blocks = 4 blocks/CU (16 waves/CU,
// was 8). Each wave owns ONE 16-q slice of one tile; waves 0-1 -> t1,
// waves 2-3 -> t0 (idle-skip past nch0, still hitting barriers).
// pr scrambled by (bx+by)&31 so each CU mixes long/short pairs.
// Fixed-shift softmax; ss2*kb folded into the per-lane shift mr (cinit
// now chunk-constant). All fragment/staging patterns from round 9.
// ---------------------------------------------------------------------------
static __device__ __forceinline__ void softmax_fixed(
    f32x4* s, bool mask, int qb, int kb, float sc2, float mrow,
    f32x4& l_vec, unsigned pbu[2][4], int l16, int quad)
{
    if (mask) {
        int fdm = qb + l16 - kb - quad * 4;   // key offset tt*16+r must be <= fdm
#pragma unroll
        for (int tt = 0; tt < 4; tt++)
#pragma unroll
            for (int r = 0; r < 4; r++)
                if (tt * 16 + r > fdm) s[tt][r] = -3e38f;
    }
    f32x4 e[4];
#pragma unroll
    for (int tt = 0; tt < 4; tt++)
#pragma unroll
        for (int r = 0; r < 4; r++)
            e[tt][r] = fexp2(s[tt][r] * sc2 - mrow);   // v_fma + v_exp
#pragma unroll
    for (int r = 0; r < 4; r++)
        l_vec[r] += (e[0][r] + e[1][r]) + (e[2][r] + e[3][r]);

#pragma unroll
    for (int p = 0; p < 2; p++) {
        pbu[p][0] = pack2bf(e[2 * p][0],     e[2 * p][1]);
        pbu[p][1] = pack2bf(e[2 * p][2],     e[2 * p][3]);
        pbu[p][2] = pack2bf(e[2 * p + 1][0], e[2 * p + 1][1]);
        pbu[p][3] = pack2bf(e[2 * p + 1][2], e[2 * p + 1][3]);
    }
}

__global__ __launch_bounds__(256) void attn_kernel(
    const unsigned short* __restrict__ Q,
    const unsigned short* __restrict__ K,
    const unsigned short* __restrict__ Vt,
    unsigned short* __restrict__ ctx)
{
    __shared__ unsigned short KV[2][8192];         // [buf][K:4096 | V:4096]

    int t = threadIdx.x, w = t >> 6, lane = t & 63;
    int l16 = lane & 15, quad = lane >> 4;
    int r7 = l16 & 7;
    int bh = blockIdx.y;
    int b_ = bh >> 4, h = bh & 15;
    int pr = (blockIdx.x + blockIdx.y) & 31;   // scrambled pair id
    int t1 = 63 - pr, t0 = pr;                 // 32-query tiles
    int nch1 = (t1 >> 1) + 1;                  // 64-key chunks needed by t1
    int nch0 = (t0 >> 1) + 1;
    int myNch = (w < 2) ? nch1 : nch0;
    int qb = ((w < 2) ? t1 : t0) * 32 + (w & 1) * 16;

    const unsigned short* Kg  = K  + (long)bh * NSEQ * HDIM;
    const unsigned short* Vtg = Vt + (long)bh * HDIM * NSEQ;

    const float log2e = 1.44269504f;
    float slope = exp2f(-0.5f * (float)(h + 1));
    float sc2 = 0.125f * log2e;     // scale * log2(e)
    float ss2 = slope * sc2;
    float ss2_64 = ss2 * 64.0f;

    const unsigned short* qp = Q + ((long)bh * NSEQ + qb + l16) * HDIM + quad * 8;
    bf16x8 aq0 = *(const bf16x8*)qp;
    bf16x8 aq1 = *(const bf16x8*)(qp + 32);

    // fixed shift mr = ss2*(q - kb); decremented per processed chunk
    float mr = ss2 * (float)(qb + l16);

    // alibi C-init (chunk-CONSTANT): cinit[tt][reg] = slope*(tt*16+quad*4+reg)
    f32x4 cinit[4];
#pragma unroll
    for (int tt = 0; tt < 4; tt++)
#pragma unroll
        for (int r = 0; r < 4; r++)
            cinit[tt][r] = slope * (float)(tt * 16 + quad * 4 + r);

    f32x4 lv = {};
    f32x4 o[4] = {};

    // hoisted staging addresses (round-9 pattern, kb-advanced per chunk)
    int b0i = t, b1i = 256 + t;
    int row0 = b0i >> 3, sw0 = (b0i & 7) ^ (row0 & 7);
    int row1 = b1i >> 3, sw1 = (b1i & 7) ^ (row1 & 7);
    const unsigned short* gk0 = Kg + row0 * HDIM + sw0 * 8;
    const unsigned short* gk1 = Kg + row1 * HDIM + sw1 * 8;
    const unsigned short* gv0 = Vtg + (long)row0 * NSEQ + sw0 * 8;
    const unsigned short* gv1 = Vtg + (long)row1 * NSEQ + sw1 * 8;

    // stage chunk 0
    {
        unsigned short* buf = KV[0];
        load16_lds(gk0, buf + b0i * 8);
        load16_lds(gk1, buf + b1i * 8);
        load16_lds(gv0, buf + 4096 + b0i * 8);
        load16_lds(gv1, buf + 4096 + b1i * 8);
    }

    for (int c = 0; c < nch1; c++) {
        __syncthreads();
        if (c + 1 < nch1) {
            int kb2 = (c + 1) * 64;
            unsigned short* buf = KV[(c + 1) & 1];
            load16_lds(gk0 + kb2 * HDIM, buf + b0i * 8);
            load16_lds(gk1 + kb2 * HDIM, buf + b1i * 8);
            load16_lds(gv0 + kb2, buf + 4096 + b0i * 8);
            load16_lds(gv1 + kb2, buf + 4096 + b1i * 8);
        }
        if (w >= 2 && c >= nch0) continue;    // wave-uniform idle past own range

        const unsigned short* Ks = KV[c & 1];
        const unsigned short* Vs = KV[c & 1] + 4096;
        int kb = c * 64;

        // ---- S^T = K·Q^T + alibi (one tile per wave)
        f32x4 s[4];
#pragma unroll
        for (int tt = 0; tt < 4; tt++) {
            int rr = tt * 16 + l16;
            bf16x8 k0 = *(const bf16x8*)(Ks + (rr * 8 + (quad ^ r7)) * 8);
            bf16x8 k1 = *(const bf16x8*)(Ks + (rr * 8 + ((quad + 4) ^ r7)) * 8);
            f32x4 z = MFMA32(k0, aq0, cinit[tt]);
            s[tt] = MFMA32(k1, aq1, z);
        }

        unsigned pb[2][4];
        softmax_fixed(s, c == myNch - 1, qb, kb, sc2, mr, lv, pb, l16, quad);
        mr -= ss2_64;

        // ---- O^T += V^T·P^T (round-6/8/9 verified pattern)
        int q2 = quad >> 1, q1b = (quad & 1) << 3;
#pragma unroll
        for (int cb = 0; cb < 4; cb++) {
            int rd = cb * 16 + l16;
            const char* vrow = (const char*)(Vs + rd * 64);
            int x7 = rd & 7;
#pragma unroll
            for (int p = 0; p < 2; p++) {
                union { bf16x8 v; uint2 u2[2]; } a;
                int sb0 = 4 * p + q2;
                int sb1 = 4 * p + 2 + q2;
                a.u2[0] = *(const uint2*)(vrow + ((sb0 ^ x7) << 4) + q1b);
                a.u2[1] = *(const uint2*)(vrow + ((sb1 ^ x7) << 4) + q1b);
                union { unsigned u[4]; bf16x8 v; } bv;
#pragma unroll
                for (int i = 0; i < 4; i++) bv.u[i] = pb[p][i];
                o[cb] = MFMA32(a.v, bv.v, o[cb]);
            }
        }
    }

    // ---- final l reduction + normalize, store ctx [b, n=q, h, d]
    {
        float lt = (lv[0] + lv[1]) + (lv[2] + lv[3]);
        lt += __shfl_xor(lt, 16);
        lt += __shfl_xor(lt, 32);
        float inv = 1.0f / lt;
        long base = (((long)b_ * NSEQ + (qb + l16)) * NH + h) * HDIM + quad * 4;
#pragma unroll
        for (int cb = 0; cb < 4; cb++) {
            uint2 u;
            u.x = pack2bf(o[cb][0] * inv, o[cb][1] * inv);
            u.y = pack2bf(o[cb][2] * inv, o[cb][3] * inv);
            *(uint2*)(ctx + base + cb * 16) = u;
        }
    }
}

// ---------------------------------------------------------------------------
// Output projection (unchanged).
// ---------------------------------------------------------------------------
__global__ __launch_bounds__(256) void out_gemm_kernel(
    const unsigned short* __restrict__ A,
    const unsigned short* __restrict__ Bt,
    const float* __restrict__ bias,
    float* __restrict__ out)
{
    __shared__ unsigned short As[128 * 32];
    __shared__ unsigned short Bs[128 * 32];
    f32x4 acc[4][4] = {};
    int m0 = blockIdx.y * 128, n0 = blockIdx.x * 128;
    gemm_tile_128(A, Bt, m0, n0, As, Bs, acc);

    int t = threadIdx.x, wave = t >> 6, lane = t & 63;
    int l16 = lane & 15, quad = lane >> 4;
    int wm = wave >> 1, wn = wave & 1;
    int rg0 = m0 + wm * 64, cg0 = n0 + wn * 64;
#pragma unroll
    for (int c = 0; c < 4; c++) {
        float bc = bias[cg0 + c * 16 + l16];
#pragma unroll
        for (int r = 0; r < 4; r++)
#pragma unroll
            for (int reg = 0; reg < 4; reg++)
                out[(long)(rg0 + r * 16 + quad * 4 + reg) * DM + cg0 + c * 16 + l16] =
                    acc[r][c][reg] + bc;
    }
}

// ---------------------------------------------------------------------------
extern "C" void kernel_launch(void* const* d_in, const int* in_sizes, int n_in,
                              void* d_out, int out_size, void* d_ws, size_t ws_size,
                              hipStream_t stream)
{
    const float* x  = (const float*)d_in[0];
    const float* wq = (const float*)d_in[1];
    const float* wk = (const float*)d_in[2];
    const float* wv = (const float*)d_in[3];
    const float* wo = (const float*)d_in[4];
    const float* bo = (const float*)d_in[5];

    char* ws = (char*)d_ws;
    unsigned short* xb    = (unsigned short*)(ws);                 // 8 MiB
    unsigned short* wqkvt = (unsigned short*)(ws + (8L  << 20));   // 6 MiB [3072][1024]
    unsigned short* wot   = (unsigned short*)(ws + (14L << 20));   // 2 MiB
    unsigned short* Qb    = (unsigned short*)(ws + (16L << 20));   // 8 MiB
    unsigned short* Kb    = (unsigned short*)(ws + (24L << 20));   // 8 MiB
    unsigned short* Vt    = (unsigned short*)(ws + (32L << 20));   // 8 MiB
    unsigned short* ctx   = (unsigned short*)(ws + (40L << 20));   // 8 MiB
    float* out = (float*)d_out;

    convert_kernel<<<2048, 256, 0, stream>>>(x, wq, wk, wv, wo, xb, wqkvt, wot);

    qkv_gemm_kernel<<<dim3(3 * DM / 128, MROWS / 128), 256, 0, stream>>>(
        xb, wqkvt, Qb, Kb, Vt);

    attn_kernel<<<dim3(32, NB * NH), 256, 0, stream>>>(Qb, Kb, Vt, ctx);

    out_gemm_kernel<<<dim3(DM / 128, MROWS / 128), 256, 0, stream>>>(
        ctx, wot, bo, out);
}

// Round 11
// 198.201 us; speedup vs baseline: 1.0869x; 1.0869x over previous
//
#include <hip/hip_runtime.h>
#include <hip/hip_bf16.h>
#include <stdint.h>

#define NH 16
#define HDIM 64
#define NB 2
#define NSEQ 2048
#define DM 1024
#define MROWS (NB * NSEQ)   // 4096

typedef __attribute__((ext_vector_type(8))) short bf16x8;
typedef __attribute__((ext_vector_type(4))) float f32x4;

#define MFMA32(a, b, c) __builtin_amdgcn_mfma_f32_16x16x32_bf16(a, b, c, 0, 0, 0)

static __device__ __forceinline__ unsigned short f2bf(float f) {
    union { float f; unsigned u; } v;
    v.f = f;
    unsigned r = v.u + 0x7fffu + ((v.u >> 16) & 1u);   // RNE
    return (unsigned short)(r >> 16);
}

static __device__ __forceinline__ unsigned pack2bf(float a, float b) {
#if __has_builtin(__builtin_amdgcn_cvt_pk_bf16_f32)
    typedef __attribute__((ext_vector_type(2))) __bf16 bf2_t;
    union { bf2_t v; unsigned u; } c;
    c.v = __builtin_amdgcn_cvt_pk_bf16_f32(a, b);
    return c.u;
#else
    return (unsigned)f2bf(a) | ((unsigned)f2bf(b) << 16);
#endif
}

static __device__ __forceinline__ float fexp2(float x) {
#if __has_builtin(__builtin_amdgcn_exp2f)
    return __builtin_amdgcn_exp2f(x);
#else
    return exp2f(x);
#endif
}

typedef __attribute__((address_space(1))) void* gas_ptr;
typedef __attribute__((address_space(3))) void* las_ptr;

// async global->LDS, 16B per lane. LDS dest must be wave-uniform base + lane*16.
static __device__ __forceinline__ void load16_lds(const void* g, void* l) {
    __builtin_amdgcn_global_load_lds((gas_ptr)(uintptr_t)g, (las_ptr)(uintptr_t)l,
                                     16, 0, 0);
}

// ---------------------------------------------------------------------------
// Convert: x -> bf16 (blocks 0..1023), weights -> bf16 transposed via LDS
// tile transpose (blocks 1024..2047).
// ---------------------------------------------------------------------------
__global__ __launch_bounds__(256) void convert_kernel(
    const float* __restrict__ x,
    const float* __restrict__ wq, const float* __restrict__ wk,
    const float* __restrict__ wv, const float* __restrict__ wo,
    unsigned short* __restrict__ xb,
    unsigned short* __restrict__ wqkvt,
    unsigned short* __restrict__ wot)
{
    __shared__ unsigned short Ts[64][66];
    int t = threadIdx.x;
    int bx = blockIdx.x;
    if (bx < 1024) {
        const float4* xs = (const float4*)x + (long)bx * 1024;
        unsigned short* xd = xb + (long)bx * 4096;
#pragma unroll
        for (int i = 0; i < 4; i++) {
            float4 v = xs[i * 256 + t];
            ushort4 o;
            o.x = f2bf(v.x); o.y = f2bf(v.y); o.z = f2bf(v.z); o.w = f2bf(v.w);
            *(ushort4*)(xd + (i * 256 + t) * 4) = o;
        }
        return;
    }
    int wi = bx - 1024;
    int wsel = wi >> 8;                 // 0..3 = q,k,v,o
    int tile = wi & 255;
    int k0 = (tile >> 4) * 64, c0 = (tile & 15) * 64;
    const float* w = (wsel == 0) ? wq : (wsel == 1) ? wk : (wsel == 2) ? wv : wo;
    int lr = t >> 6, lc = t & 63;
#pragma unroll
    for (int rr = 0; rr < 16; rr++) {
        int row = rr * 4 + lr;
        Ts[row][lc] = f2bf(w[(long)(k0 + row) * DM + c0 + lc]);
    }
    __syncthreads();
    unsigned short* dst = (wsel == 3) ? wot : (wqkvt + (long)wsel * DM * DM);
#pragma unroll
    for (int rr = 0; rr < 16; rr++) {
        int crow = rr * 4 + lr;
        dst[(long)(c0 + crow) * DM + k0 + lc] = Ts[lc][crow];
    }
}

// ---------------------------------------------------------------------------
// m97-style 128x128 GEMM core (unchanged).
// ---------------------------------------------------------------------------
static __device__ __forceinline__ void gemm_tile_128(
    const unsigned short* __restrict__ A, const unsigned short* __restrict__ Bt,
    int m0, int n0, unsigned short* As, unsigned short* Bs, f32x4 (&acc)[4][4])
{
    int t = threadIdx.x;
    int lane = t & 63;
    int wave = t >> 6;
    int l16 = lane & 15, quad = lane >> 4;
    int wm = wave >> 1, wn = wave & 1;

    int off0 = t * 16;
    int off1 = off0 + 4096;
    const char* ga0 = (const char*)(A + (long)(m0 + (off0 >> 6)) * DM) + (off0 & 63);
    const char* ga1 = (const char*)(A + (long)(m0 + (off1 >> 6)) * DM) + (off1 & 63);
    const char* gb0 = (const char*)(Bt + (long)(n0 + (off0 >> 6)) * DM) + (off0 & 63);
    const char* gb1 = (const char*)(Bt + (long)(n0 + (off1 >> 6)) * DM) + (off1 & 63);
    char* sa0 = (char*)As + off0;
    char* sa1 = (char*)As + off1;
    char* sb0 = (char*)Bs + off0;
    char* sb1 = (char*)Bs + off1;

    const unsigned short* fa = As + (wm * 64 + l16) * 32 + quad * 8;
    const unsigned short* fb = Bs + (wn * 64 + l16) * 32 + quad * 8;

    for (int kk = 0; kk < DM; kk += 32) {
        load16_lds(ga0 + kk * 2, sa0);
        load16_lds(ga1 + kk * 2, sa1);
        load16_lds(gb0 + kk * 2, sb0);
        load16_lds(gb1 + kk * 2, sb1);
        __syncthreads();
        bf16x8 af[4], bf[4];
#pragma unroll
        for (int r = 0; r < 4; r++) af[r] = *(const bf16x8*)(fa + r * 16 * 32);
#pragma unroll
        for (int c = 0; c < 4; c++) bf[c] = *(const bf16x8*)(fb + c * 16 * 32);
#pragma unroll
        for (int r = 0; r < 4; r++)
#pragma unroll
            for (int c = 0; c < 4; c++)
                acc[r][c] = MFMA32(af[r], bf[c], acc[r][c]);
        __syncthreads();
    }
}

// ---------------------------------------------------------------------------
// Fused QKV GEMM (unchanged from round 9).
// ---------------------------------------------------------------------------
__global__ __launch_bounds__(256) void qkv_gemm_kernel(
    const unsigned short* __restrict__ A,
    const unsigned short* __restrict__ Bt,
    unsigned short* __restrict__ Qo, unsigned short* __restrict__ Ko,
    unsigned short* __restrict__ Vt)
{
    __shared__ unsigned short As[128 * 32];
    __shared__ unsigned short Bs[128 * 32];
    __shared__ unsigned short Tw[4][16][72];

    f32x4 acc[4][4] = {};
    int m0 = blockIdx.y * 128, n0 = blockIdx.x * 128;
    gemm_tile_128(A, Bt, m0, n0, As, Bs, acc);

    int t = threadIdx.x, wave = t >> 6, lane = t & 63;
    int l16 = lane & 15, quad = lane >> 4;
    int wm = wave >> 1, wn = wave & 1;
    int rg0 = m0 + wm * 64;
    int cg0 = n0 + wn * 64;
    int z = cg0 >> 10;
    int b_ = rg0 >> 11;
    int nb0 = rg0 & (NSEQ - 1);
    int h = (cg0 & 1023) >> 6;
    long bh = (long)(b_ * NH + h);

    if (z < 2) {
        unsigned short* dst = (z == 0 ? Qo : Ko) + bh * NSEQ * HDIM;
#pragma unroll
        for (int r = 0; r < 4; r++)
#pragma unroll
            for (int reg = 0; reg < 4; reg++) {
                long rowb = (long)(nb0 + r * 16 + quad * 4 + reg) * HDIM;
#pragma unroll
                for (int c = 0; c < 4; c++)
                    dst[rowb + c * 16 + l16] = f2bf(acc[r][c][reg]);
            }
    } else {
        unsigned short* dst = Vt + bh * HDIM * NSEQ;
#pragma unroll
        for (int c = 0; c < 4; c++) {
#pragma unroll
            for (int r = 0; r < 4; r++) {
                ushort4 u;
                u.x = f2bf(acc[r][c][0]); u.y = f2bf(acc[r][c][1]);
                u.z = f2bf(acc[r][c][2]); u.w = f2bf(acc[r][c][3]);
                *(ushort4*)&Tw[wave][l16][r * 16 + quad * 4] = u;   // [hd][n]
            }
#pragma unroll
            for (int j = 0; j < 4; j++) {
                int lrow = j * 4 + quad;
                ushort4 u = *(const ushort4*)&Tw[wave][lrow][l16 * 4];
                *(ushort4*)(dst + (long)(c * 16 + lrow) * NSEQ + nb0 + l16 * 4) = u;
            }
        }
    }
}

// ---------------------------------------------------------------------------
// Flash attention v9 = round-9 structure with XCD-local grid. Grid is
// (bh=32, pr=16) so linear block id = bh + 32*pr and XCD = id%8 = bh%8:
// ALL 16 pair-blocks of one head land on ONE XCD -> per-XCD K/V working
// set = 4 heads x 512KB = 2MB <= 4MB L2 (was 16MB thrash). Every other
// byte identical to round 9: pair-fused 64q tiles, merged shared-fragment
// pass, fixed-shift softmax, double-buffered swizzled KV staging.
// ---------------------------------------------------------------------------
static __device__ __forceinline__ void stage_kv(
    const unsigned short* __restrict__ Kg,
    const unsigned short* __restrict__ Vtg,
    int kb, unsigned short* buf, int t)
{
#pragma unroll
    for (int r = 0; r < 2; r++) {
        int b = r * 256 + t;
        int row = b >> 3, sp = b & 7;
        int s = sp ^ (row & 7);
        load16_lds(Kg + (long)(kb + row) * HDIM + s * 8, buf + b * 8);
    }
#pragma unroll
    for (int r = 0; r < 2; r++) {
        int b = r * 256 + t;
        int row = b >> 3, sp = b & 7;
        int s = sp ^ (row & 7);
        load16_lds(Vtg + (long)row * NSEQ + kb + s * 8, buf + 4096 + b * 8);
    }
}

// fixed-shift softmax; emits pb packing: key = (2p+(j>>2))*16 + quad*4 + (j&3)
static __device__ __forceinline__ void softmax_fixed(
    f32x4* s, bool mask, int qb, int kb, float sc2, float mrow,
    f32x4& l_vec, unsigned pbu[2][4], int l16, int quad)
{
    if (mask) {
        int fdm = qb + l16 - kb - quad * 4;   // key offset tt*16+r must be <= fdm
#pragma unroll
        for (int tt = 0; tt < 4; tt++)
#pragma unroll
            for (int r = 0; r < 4; r++)
                if (tt * 16 + r > fdm) s[tt][r] = -3e38f;
    }
    f32x4 e[4];
#pragma unroll
    for (int tt = 0; tt < 4; tt++)
#pragma unroll
        for (int r = 0; r < 4; r++)
            e[tt][r] = fexp2(s[tt][r] * sc2 - mrow);   // v_fma + v_exp
#pragma unroll
    for (int r = 0; r < 4; r++)
        l_vec[r] += (e[0][r] + e[1][r]) + (e[2][r] + e[3][r]);

#pragma unroll
    for (int p = 0; p < 2; p++) {
        pbu[p][0] = pack2bf(e[2 * p][0],     e[2 * p][1]);
        pbu[p][1] = pack2bf(e[2 * p][2],     e[2 * p][3]);
        pbu[p][2] = pack2bf(e[2 * p + 1][0], e[2 * p + 1][1]);
        pbu[p][3] = pack2bf(e[2 * p + 1][2], e[2 * p + 1][3]);
    }
}

__global__ __launch_bounds__(256) void attn_kernel(
    const unsigned short* __restrict__ Q,
    const unsigned short* __restrict__ K,
    const unsigned short* __restrict__ Vt,
    unsigned short* __restrict__ ctx)
{
    __shared__ unsigned short KV[2][8192];         // [buf][K:4096 | V:4096]

    int t = threadIdx.x, w = t >> 6, lane = t & 63;
    int l16 = lane & 15, quad = lane >> 4;
    int r7 = l16 & 7;
    int bh = blockIdx.x;            // XCD = bh % 8 (L2 locality)
    int b_ = bh >> 4, h = bh & 15;
    int pr = blockIdx.y;            // pair id 0..15
    int t1 = 31 - pr, t0 = pr;
    int nch = t1 + 1;               // 17..32 chunks; 33 tile-chunk units/block

    const unsigned short* Kg  = K  + (long)bh * NSEQ * HDIM;
    const unsigned short* Vtg = Vt + (long)bh * HDIM * NSEQ;

    const float log2e = 1.44269504f;
    float slope = exp2f(-0.5f * (float)(h + 1));
    float sc2 = 0.125f * log2e;     // scale * log2(e)
    float ss2 = slope * sc2;

    int qb1 = t1 * 64 + w * 16;
    int qb0 = t0 * 64 + w * 16;
    const unsigned short* qp1 = Q + ((long)bh * NSEQ + qb1 + l16) * HDIM + quad * 8;
    const unsigned short* qp0 = Q + ((long)bh * NSEQ + qb0 + l16) * HDIM + quad * 8;
    bf16x8 aq1_0 = *(const bf16x8*)qp1;
    bf16x8 aq1_1 = *(const bf16x8*)(qp1 + 32);
    bf16x8 aq0_0 = *(const bf16x8*)qp0;
    bf16x8 aq0_1 = *(const bf16x8*)(qp0 + 32);

    // lane-constant fixed shifts (exactly the dropped row term of the ref)
    float mrow1 = ss2 * (float)(qb1 + l16);
    float mrow0 = ss2 * (float)(qb0 + l16);

    // alibi C-init: cinit[tt][reg] = slope * (kb + tt*16 + quad*4 + reg)
    f32x4 cinit[4];
#pragma unroll
    for (int tt = 0; tt < 4; tt++)
#pragma unroll
        for (int r = 0; r < 4; r++)
            cinit[tt][r] = slope * (float)(tt * 16 + quad * 4 + r);
    float sl64 = slope * 64.0f;

    f32x4 l1v = {}, l0v = {};
    f32x4 o1[4] = {}, o0[4] = {};

    stage_kv(Kg, Vtg, 0, KV[0], t);

    for (int c = 0; c < nch; c++) {
        __syncthreads();
        if (c + 1 < nch) stage_kv(Kg, Vtg, (c + 1) * 64, KV[(c + 1) & 1], t);

        const unsigned short* Ks = KV[c & 1];
        const unsigned short* Vs = KV[c & 1] + 4096;
        int kb = c * 64;
        bool do0 = (c <= t0);

        // ---- S^T = K·Q^T + alibi for both tiles, shared K fragments
        f32x4 s1[4], s0[4];
#pragma unroll
        for (int tt = 0; tt < 4; tt++) {
            int rr = tt * 16 + l16;
            bf16x8 k0 = *(const bf16x8*)(Ks + (rr * 8 + (quad ^ r7)) * 8);
            bf16x8 k1 = *(const bf16x8*)(Ks + (rr * 8 + ((quad + 4) ^ r7)) * 8);
            f32x4 z1 = MFMA32(k0, aq1_0, cinit[tt]);
            s1[tt] = MFMA32(k1, aq1_1, z1);
            if (do0) {
                f32x4 z0 = MFMA32(k0, aq0_0, cinit[tt]);
                s0[tt] = MFMA32(k1, aq0_1, z0);
            }
        }

        unsigned pb1[2][4], pb0[2][4];
        softmax_fixed(s1, c == nch - 1, qb1, kb, sc2, mrow1, l1v, pb1, l16, quad);
        if (do0)
            softmax_fixed(s0, c == t0, qb0, kb, sc2, mrow0, l0v, pb0, l16, quad);

        // ---- O^T += V^T·P^T, shared A-fragments (round-6/8/9 verified pattern)
        int q2 = quad >> 1, q1b = (quad & 1) << 3;
#pragma unroll
        for (int cb = 0; cb < 4; cb++) {
            int rd = cb * 16 + l16;
            const char* vrow = (const char*)(Vs + rd * 64);
            int x7 = rd & 7;
#pragma unroll
            for (int p = 0; p < 2; p++) {
                union { bf16x8 v; uint2 u2[2]; } a;
                int sb0 = 4 * p + q2;
                int sb1 = 4 * p + 2 + q2;
                a.u2[0] = *(const uint2*)(vrow + ((sb0 ^ x7) << 4) + q1b);
                a.u2[1] = *(const uint2*)(vrow + ((sb1 ^ x7) << 4) + q1b);
                union { unsigned u[4]; bf16x8 v; } b1v;
#pragma unroll
                for (int i = 0; i < 4; i++) b1v.u[i] = pb1[p][i];
                o1[cb] = MFMA32(a.v, b1v.v, o1[cb]);
                if (do0) {
                    union { unsigned u[4]; bf16x8 v; } b0v;
#pragma unroll
                    for (int i = 0; i < 4; i++) b0v.u[i] = pb0[p][i];
                    o0[cb] = MFMA32(a.v, b0v.v, o0[cb]);
                }
            }
        }

#pragma unroll
        for (int tt = 0; tt < 4; tt++)
#pragma unroll
            for (int r = 0; r < 4; r++)
                cinit[tt][r] += sl64;
    }

    // ---- final l reduction (once) + normalize, store ctx [b, n=q, h, d]
    {
        float lt1 = (l1v[0] + l1v[1]) + (l1v[2] + l1v[3]);
        lt1 += __shfl_xor(lt1, 16);
        lt1 += __shfl_xor(lt1, 32);
        float lt0 = (l0v[0] + l0v[1]) + (l0v[2] + l0v[3]);
        lt0 += __shfl_xor(lt0, 16);
        lt0 += __shfl_xor(lt0, 32);
        float inv1 = 1.0f / lt1;
        float inv0 = 1.0f / lt0;
        long base1 = (((long)b_ * NSEQ + (qb1 + l16)) * NH + h) * HDIM + quad * 4;
        long base0 = (((long)b_ * NSEQ + (qb0 + l16)) * NH + h) * HDIM + quad * 4;
#pragma unroll
        for (int cb = 0; cb < 4; cb++) {
            uint2 u1, u0;
            u1.x = pack2bf(o1[cb][0] * inv1, o1[cb][1] * inv1);
            u1.y = pack2bf(o1[cb][2] * inv1, o1[cb][3] * inv1);
            u0.x = pack2bf(o0[cb][0] * inv0, o0[cb][1] * inv0);
            u0.y = pack2bf(o0[cb][2] * inv0, o0[cb][3] * inv0);
            *(uint2*)(ctx + base1 + cb * 16) = u1;
            *(uint2*)(ctx + base0 + cb * 16) = u0;
        }
    }
}

// ---------------------------------------------------------------------------
// Output projection (unchanged).
// ---------------------------------------------------------------------------
__global__ __launch_bounds__(256) void out_gemm_kernel(
    const unsigned short* __restrict__ A,
    const unsigned short* __restrict__ Bt,
    const float* __restrict__ bias,
    float* __restrict__ out)
{
    __shared__ unsigned short As[128 * 32];
    __shared__ unsigned short Bs[128 * 32];
    f32x4 acc[4][4] = {};
    int m0 = blockIdx.y * 128, n0 = blockIdx.x * 128;
    gemm_tile_128(A, Bt, m0, n0, As, Bs, acc);

    int t = threadIdx.x, wave = t >> 6, lane = t & 63;
    int l16 = lane & 15, quad = lane >> 4;
    int wm = wave >> 1, wn = wave & 1;
    int rg0 = m0 + wm * 64, cg0 = n0 + wn * 64;
#pragma unroll
    for (int c = 0; c < 4; c++) {
        float bc = bias[cg0 + c * 16 + l16];
#pragma unroll
        for (int r = 0; r < 4; r++)
#pragma unroll
            for (int reg = 0; reg < 4; reg++)
                out[(long)(rg0 + r * 16 + quad * 4 + reg) * DM + cg0 + c * 16 + l16] =
                    acc[r][c][reg] + bc;
    }
}

// ---------------------------------------------------------------------------
extern "C" void kernel_launch(void* const* d_in, const int* in_sizes, int n_in,
                              void* d_out, int out_size, void* d_ws, size_t ws_size,
                              hipStream_t stream)
{
    const float* x  = (const float*)d_in[0];
    const float* wq = (const float*)d_in[1];
    const float* wk = (const float*)d_in[2];
    const float* wv = (const float*)d_in[3];
    const float* wo = (const float*)d_in[4];
    const float* bo = (const float*)d_in[5];

    char* ws = (char*)d_ws;
    unsigned short* xb    = (unsigned short*)(ws);                 // 8 MiB
    unsigned short* wqkvt = (unsigned short*)(ws + (8L  << 20));   // 6 MiB [3072][1024]
    unsigned short* wot   = (unsigned short*)(ws + (14L << 20));   // 2 MiB
    unsigned short* Qb    = (unsigned short*)(ws + (16L << 20));   // 8 MiB
    unsigned short* Kb    = (unsigned short*)(ws + (24L << 20));   // 8 MiB
    unsigned short* Vt    = (unsigned short*)(ws + (32L << 20));   // 8 MiB
    unsigned short* ctx   = (unsigned short*)(ws + (40L << 20));   // 8 MiB
    float* out = (float*)d_out;

    convert_kernel<<<2048, 256, 0, stream>>>(x, wq, wk, wv, wo, xb, wqkvt, wot);

    qkv_gemm_kernel<<<dim3(3 * DM / 128, MROWS / 128), 256, 0, stream>>>(
        xb, wqkvt, Qb, Kb, Vt);

    attn_kernel<<<dim3(NB * NH, 16), 256, 0, stream>>>(Qb, Kb, Vt, ctx);

    out_gemm_kernel<<<dim3(DM / 128, MROWS / 128), 256, 0, stream>>>(
        ctx, wot, bo, out);
}

// Round 12
// 190.644 us; speedup vs baseline: 1.1300x; 1.0396x over previous
//
#include <hip/hip_runtime.h>
#include <hip/hip_bf16.h>
#include <stdint.h>

#define NH 16
#define HDIM 64
#define NB 2
#define NSEQ 2048
#define DM 1024
#define MROWS (NB * NSEQ)   // 4096

typedef __attribute__((ext_vector_type(8))) short bf16x8;
typedef __attribute__((ext_vector_type(4))) float f32x4;

#define MFMA32(a, b, c) __builtin_amdgcn_mfma_f32_16x16x32_bf16(a, b, c, 0, 0, 0)

static __device__ __forceinline__ unsigned short f2bf(float f) {
    union { float f; unsigned u; } v;
    v.f = f;
    unsigned r = v.u + 0x7fffu + ((v.u >> 16) & 1u);   // RNE
    return (unsigned short)(r >> 16);
}

static __device__ __forceinline__ unsigned pack2bf(float a, float b) {
#if __has_builtin(__builtin_amdgcn_cvt_pk_bf16_f32)
    typedef __attribute__((ext_vector_type(2))) __bf16 bf2_t;
    union { bf2_t v; unsigned u; } c;
    c.v = __builtin_amdgcn_cvt_pk_bf16_f32(a, b);
    return c.u;
#else
    return (unsigned)f2bf(a) | ((unsigned)f2bf(b) << 16);
#endif
}

static __device__ __forceinline__ float fexp2(float x) {
#if __has_builtin(__builtin_amdgcn_exp2f)
    return __builtin_amdgcn_exp2f(x);
#else
    return exp2f(x);
#endif
}

typedef __attribute__((address_space(1))) void* gas_ptr;
typedef __attribute__((address_space(3))) void* las_ptr;

// async global->LDS, 16B per lane. LDS dest must be wave-uniform base + lane*16.
static __device__ __forceinline__ void load16_lds(const void* g, void* l) {
    __builtin_amdgcn_global_load_lds((gas_ptr)(uintptr_t)g, (las_ptr)(uintptr_t)l,
                                     16, 0, 0);
}

// ---------------------------------------------------------------------------
// Convert: x -> bf16 (blocks 0..1023), weights -> bf16 transposed via LDS
// tile transpose (blocks 1024..2047).
// ---------------------------------------------------------------------------
__global__ __launch_bounds__(256) void convert_kernel(
    const float* __restrict__ x,
    const float* __restrict__ wq, const float* __restrict__ wk,
    const float* __restrict__ wv, const float* __restrict__ wo,
    unsigned short* __restrict__ xb,
    unsigned short* __restrict__ wqkvt,
    unsigned short* __restrict__ wot)
{
    __shared__ unsigned short Ts[64][66];
    int t = threadIdx.x;
    int bx = blockIdx.x;
    if (bx < 1024) {
        const float4* xs = (const float4*)x + (long)bx * 1024;
        unsigned short* xd = xb + (long)bx * 4096;
#pragma unroll
        for (int i = 0; i < 4; i++) {
            float4 v = xs[i * 256 + t];
            ushort4 o;
            o.x = f2bf(v.x); o.y = f2bf(v.y); o.z = f2bf(v.z); o.w = f2bf(v.w);
            *(ushort4*)(xd + (i * 256 + t) * 4) = o;
        }
        return;
    }
    int wi = bx - 1024;
    int wsel = wi >> 8;                 // 0..3 = q,k,v,o
    int tile = wi & 255;
    int k0 = (tile >> 4) * 64, c0 = (tile & 15) * 64;
    const float* w = (wsel == 0) ? wq : (wsel == 1) ? wk : (wsel == 2) ? wv : wo;
    int lr = t >> 6, lc = t & 63;
#pragma unroll
    for (int rr = 0; rr < 16; rr++) {
        int row = rr * 4 + lr;
        Ts[row][lc] = f2bf(w[(long)(k0 + row) * DM + c0 + lc]);
    }
    __syncthreads();
    unsigned short* dst = (wsel == 3) ? wot : (wqkvt + (long)wsel * DM * DM);
#pragma unroll
    for (int rr = 0; rr < 16; rr++) {
        int crow = rr * 4 + lr;
        dst[(long)(c0 + crow) * DM + k0 + lc] = Ts[lc][crow];
    }
}

// ---------------------------------------------------------------------------
// m97-style 128x128 GEMM core (unchanged).
// ---------------------------------------------------------------------------
static __device__ __forceinline__ void gemm_tile_128(
    const unsigned short* __restrict__ A, const unsigned short* __restrict__ Bt,
    int m0, int n0, unsigned short* As, unsigned short* Bs, f32x4 (&acc)[4][4])
{
    int t = threadIdx.x;
    int lane = t & 63;
    int wave = t >> 6;
    int l16 = lane & 15, quad = lane >> 4;
    int wm = wave >> 1, wn = wave & 1;

    int off0 = t * 16;
    int off1 = off0 + 4096;
    const char* ga0 = (const char*)(A + (long)(m0 + (off0 >> 6)) * DM) + (off0 & 63);
    const char* ga1 = (const char*)(A + (long)(m0 + (off1 >> 6)) * DM) + (off1 & 63);
    const char* gb0 = (const char*)(Bt + (long)(n0 + (off0 >> 6)) * DM) + (off0 & 63);
    const char* gb1 = (const char*)(Bt + (long)(n0 + (off1 >> 6)) * DM) + (off1 & 63);
    char* sa0 = (char*)As + off0;
    char* sa1 = (char*)As + off1;
    char* sb0 = (char*)Bs + off0;
    char* sb1 = (char*)Bs + off1;

    const unsigned short* fa = As + (wm * 64 + l16) * 32 + quad * 8;
    const unsigned short* fb = Bs + (wn * 64 + l16) * 32 + quad * 8;

    for (int kk = 0; kk < DM; kk += 32) {
        load16_lds(ga0 + kk * 2, sa0);
        load16_lds(ga1 + kk * 2, sa1);
        load16_lds(gb0 + kk * 2, sb0);
        load16_lds(gb1 + kk * 2, sb1);
        __syncthreads();
        bf16x8 af[4], bf[4];
#pragma unroll
        for (int r = 0; r < 4; r++) af[r] = *(const bf16x8*)(fa + r * 16 * 32);
#pragma unroll
        for (int c = 0; c < 4; c++) bf[c] = *(const bf16x8*)(fb + c * 16 * 32);
#pragma unroll
        for (int r = 0; r < 4; r++)
#pragma unroll
            for (int c = 0; c < 4; c++)
                acc[r][c] = MFMA32(af[r], bf[c], acc[r][c]);
        __syncthreads();
    }
}

// ---------------------------------------------------------------------------
// Fused QKV GEMM (unchanged from round 11).
// ---------------------------------------------------------------------------
__global__ __launch_bounds__(256) void qkv_gemm_kernel(
    const unsigned short* __restrict__ A,
    const unsigned short* __restrict__ Bt,
    unsigned short* __restrict__ Qo, unsigned short* __restrict__ Ko,
    unsigned short* __restrict__ Vt)
{
    __shared__ unsigned short As[128 * 32];
    __shared__ unsigned short Bs[128 * 32];
    __shared__ unsigned short Tw[4][16][72];

    f32x4 acc[4][4] = {};
    int m0 = blockIdx.y * 128, n0 = blockIdx.x * 128;
    gemm_tile_128(A, Bt, m0, n0, As, Bs, acc);

    int t = threadIdx.x, wave = t >> 6, lane = t & 63;
    int l16 = lane & 15, quad = lane >> 4;
    int wm = wave >> 1, wn = wave & 1;
    int rg0 = m0 + wm * 64;
    int cg0 = n0 + wn * 64;
    int z = cg0 >> 10;
    int b_ = rg0 >> 11;
    int nb0 = rg0 & (NSEQ - 1);
    int h = (cg0 & 1023) >> 6;
    long bh = (long)(b_ * NH + h);

    if (z < 2) {
        unsigned short* dst = (z == 0 ? Qo : Ko) + bh * NSEQ * HDIM;
#pragma unroll
        for (int r = 0; r < 4; r++)
#pragma unroll
            for (int reg = 0; reg < 4; reg++) {
                long rowb = (long)(nb0 + r * 16 + quad * 4 + reg) * HDIM;
#pragma unroll
                for (int c = 0; c < 4; c++)
                    dst[rowb + c * 16 + l16] = f2bf(acc[r][c][reg]);
            }
    } else {
        unsigned short* dst = Vt + bh * HDIM * NSEQ;
#pragma unroll
        for (int c = 0; c < 4; c++) {
#pragma unroll
            for (int r = 0; r < 4; r++) {
                ushort4 u;
                u.x = f2bf(acc[r][c][0]); u.y = f2bf(acc[r][c][1]);
                u.z = f2bf(acc[r][c][2]); u.w = f2bf(acc[r][c][3]);
                *(ushort4*)&Tw[wave][l16][r * 16 + quad * 4] = u;   // [hd][n]
            }
#pragma unroll
            for (int j = 0; j < 4; j++) {
                int lrow = j * 4 + quad;
                ushort4 u = *(const ushort4*)&Tw[wave][lrow][l16 * 4];
                *(ushort4*)(dst + (long)(c * 16 + lrow) * NSEQ + nb0 + l16 * 4) = u;
            }
        }
    }
}

// ---------------------------------------------------------------------------
// fixed-shift softmax; emits pb packing: key = (2p+(j>>2))*16 + quad*4 + (j&3)
// ---------------------------------------------------------------------------
static __device__ __forceinline__ void softmax_fixed(
    f32x4* s, bool mask, int qb, int kb, float sc2, float mrow,
    f32x4& l_vec, unsigned pbu[2][4], int l16, int quad)
{
    if (mask) {
        int fdm = qb + l16 - kb - quad * 4;   // key offset tt*16+r must be <= fdm
#pragma unroll
        for (int tt = 0; tt < 4; tt++)
#pragma unroll
            for (int r = 0; r < 4; r++)
                if (tt * 16 + r > fdm) s[tt][r] = -3e38f;
    }
    f32x4 e[4];
#pragma unroll
    for (int tt = 0; tt < 4; tt++)
#pragma unroll
        for (int r = 0; r < 4; r++)
            e[tt][r] = fexp2(s[tt][r] * sc2 - mrow);   // v_fma + v_exp
#pragma unroll
    for (int r = 0; r < 4; r++)
        l_vec[r] += (e[0][r] + e[1][r]) + (e[2][r] + e[3][r]);

#pragma unroll
    for (int p = 0; p < 2; p++) {
        pbu[p][0] = pack2bf(e[2 * p][0],     e[2 * p][1]);
        pbu[p][1] = pack2bf(e[2 * p][2],     e[2 * p][3]);
        pbu[p][2] = pack2bf(e[2 * p + 1][0], e[2 * p + 1][1]);
        pbu[p][3] = pack2bf(e[2 * p + 1][2], e[2 * p + 1][3]);
    }
}

// ---------------------------------------------------------------------------
// Flash attention v10: 512-thread (8-wave) blocks, one (t1,t0) pair each.
// Waves 0-3 -> t1's four 16-q slices; waves 4-7 -> t0's (idle-skip past
// their range, barrier-safe). One 16KB K/V chunk staged per block per
// chunk serves all 8 waves (sharing preserved); waves/SIMD 2 -> 4.
// Grid (bh=32, pr=16): XCD = bh%8 L2 locality (round-11 win).
// alibi C-init chunk-constant; mrow recomputed per chunk (continue-safe).
// ---------------------------------------------------------------------------
__global__ __launch_bounds__(512) void attn_kernel(
    const unsigned short* __restrict__ Q,
    const unsigned short* __restrict__ K,
    const unsigned short* __restrict__ Vt,
    unsigned short* __restrict__ ctx)
{
    __shared__ unsigned short KV[2][8192];         // [buf][K:4096 | V:4096]

    int t = threadIdx.x, w = t >> 6, lane = t & 63;
    int l16 = lane & 15, quad = lane >> 4;
    int r7 = l16 & 7;
    int bh = blockIdx.x;            // XCD = bh % 8 (L2 locality)
    int b_ = bh >> 4, h = bh & 15;
    int pr = blockIdx.y;            // pair id 0..15
    int t1 = 31 - pr, t0 = pr;
    int nch = t1 + 1;               // chunks staged by the block
    bool isT0 = (w >= 4);
    int myTile = isT0 ? t0 : t1;
    int myNch = myTile + 1;
    int qb = myTile * 64 + (w & 3) * 16;

    const unsigned short* Kg  = K  + (long)bh * NSEQ * HDIM;
    const unsigned short* Vtg = Vt + (long)bh * HDIM * NSEQ;

    const float log2e = 1.44269504f;
    float slope = exp2f(-0.5f * (float)(h + 1));
    float sc2 = 0.125f * log2e;     // scale * log2(e)
    float ss2 = slope * sc2;

    const unsigned short* qp = Q + ((long)bh * NSEQ + qb + l16) * HDIM + quad * 8;
    bf16x8 aq0 = *(const bf16x8*)qp;
    bf16x8 aq1 = *(const bf16x8*)(qp + 32);

    // alibi C-init (chunk-constant): cinit[tt][r] = slope*(tt*16+quad*4+r)
    f32x4 cinit[4];
#pragma unroll
    for (int tt = 0; tt < 4; tt++)
#pragma unroll
        for (int r = 0; r < 4; r++)
            cinit[tt][r] = slope * (float)(tt * 16 + quad * 4 + r);

    f32x4 lv = {};
    f32x4 o[4] = {};

    // staging: 512 threads x 16B cover K (8KB) and V (8KB) in one pass each
    int row = t >> 3, sp = t & 7, sw = sp ^ (row & 7);
    const unsigned short* gk = Kg + row * HDIM + sw * 8;
    const unsigned short* gv = Vtg + (long)row * NSEQ + sw * 8;

    {   // stage chunk 0
        unsigned short* buf = KV[0];
        load16_lds(gk, buf + t * 8);
        load16_lds(gv, buf + 4096 + t * 8);
    }

    for (int c = 0; c < nch; c++) {
        __syncthreads();
        if (c + 1 < nch) {
            int kb2 = (c + 1) * 64;
            unsigned short* buf = KV[(c + 1) & 1];
            load16_lds(gk + kb2 * HDIM, buf + t * 8);
            load16_lds(gv + kb2, buf + 4096 + t * 8);
        }
        if (isT0 && c >= myNch) continue;   // wave-uniform idle (barrier-safe)

        const unsigned short* Ks = KV[c & 1];
        const unsigned short* Vs = KV[c & 1] + 4096;
        int kb = c * 64;

        // ---- S^T = K·Q^T + alibi (one 16-q slice per wave)
        f32x4 s[4];
#pragma unroll
        for (int tt = 0; tt < 4; tt++) {
            int rr = tt * 16 + l16;
            bf16x8 k0 = *(const bf16x8*)(Ks + (rr * 8 + (quad ^ r7)) * 8);
            bf16x8 k1 = *(const bf16x8*)(Ks + (rr * 8 + ((quad + 4) ^ r7)) * 8);
            f32x4 z = MFMA32(k0, aq0, cinit[tt]);
            s[tt] = MFMA32(k1, aq1, z);
        }

        float mrow = ss2 * (float)(qb + l16 - kb);
        unsigned pb[2][4];
        softmax_fixed(s, c == myNch - 1, qb, kb, sc2, mrow, lv, pb, l16, quad);

        // ---- O^T += V^T·P^T (round-6/8/9/11 verified pattern)
        int q2 = quad >> 1, q1b = (quad & 1) << 3;
#pragma unroll
        for (int cb = 0; cb < 4; cb++) {
            int rd = cb * 16 + l16;
            const char* vrow = (const char*)(Vs + rd * 64);
            int x7 = rd & 7;
#pragma unroll
            for (int p = 0; p < 2; p++) {
                union { bf16x8 v; uint2 u2[2]; } a;
                int sb0 = 4 * p + q2;
                int sb1 = 4 * p + 2 + q2;
                a.u2[0] = *(const uint2*)(vrow + ((sb0 ^ x7) << 4) + q1b);
                a.u2[1] = *(const uint2*)(vrow + ((sb1 ^ x7) << 4) + q1b);
                union { unsigned u[4]; bf16x8 v; } bv;
#pragma unroll
                for (int i = 0; i < 4; i++) bv.u[i] = pb[p][i];
                o[cb] = MFMA32(a.v, bv.v, o[cb]);
            }
        }
    }

    // ---- final l reduction + normalize, store ctx [b, n=q, h, d]
    {
        float lt = (lv[0] + lv[1]) + (lv[2] + lv[3]);
        lt += __shfl_xor(lt, 16);
        lt += __shfl_xor(lt, 32);
        float inv = 1.0f / lt;
        long base = (((long)b_ * NSEQ + (qb + l16)) * NH + h) * HDIM + quad * 4;
#pragma unroll
        for (int cb = 0; cb < 4; cb++) {
            uint2 u;
            u.x = pack2bf(o[cb][0] * inv, o[cb][1] * inv);
            u.y = pack2bf(o[cb][2] * inv, o[cb][3] * inv);
            *(uint2*)(ctx + base + cb * 16) = u;
        }
    }
}

// ---------------------------------------------------------------------------
// Output projection (unchanged).
// ---------------------------------------------------------------------------
__global__ __launch_bounds__(256) void out_gemm_kernel(
    const unsigned short* __restrict__ A,
    const unsigned short* __restrict__ Bt,
    const float* __restrict__ bias,
    float* __restrict__ out)
{
    __shared__ unsigned short As[128 * 32];
    __shared__ unsigned short Bs[128 * 32];
    f32x4 acc[4][4] = {};
    int m0 = blockIdx.y * 128, n0 = blockIdx.x * 128;
    gemm_tile_128(A, Bt, m0, n0, As, Bs, acc);

    int t = threadIdx.x, wave = t >> 6, lane = t & 63;
    int l16 = lane & 15, quad = lane >> 4;
    int wm = wave >> 1, wn = wave & 1;
    int rg0 = m0 + wm * 64, cg0 = n0 + wn * 64;
#pragma unroll
    for (int c = 0; c < 4; c++) {
        float bc = bias[cg0 + c * 16 + l16];
#pragma unroll
        for (int r = 0; r < 4; r++)
#pragma unroll
            for (int reg = 0; reg < 4; reg++)
                out[(long)(rg0 + r * 16 + quad * 4 + reg) * DM + cg0 + c * 16 + l16] =
                    acc[r][c][reg] + bc;
    }
}

// ---------------------------------------------------------------------------
extern "C" void kernel_launch(void* const* d_in, const int* in_sizes, int n_in,
                              void* d_out, int out_size, void* d_ws, size_t ws_size,
                              hipStream_t stream)
{
    const float* x  = (const float*)d_in[0];
    const float* wq = (const float*)d_in[1];
    const float* wk = (const float*)d_in[2];
    const float* wv = (const float*)d_in[3];
    const float* wo = (const float*)d_in[4];
    const float* bo = (const float*)d_in[5];

    char* ws = (char*)d_ws;
    unsigned short* xb    = (unsigned short*)(ws);                 // 8 MiB
    unsigned short* wqkvt = (unsigned short*)(ws + (8L  << 20));   // 6 MiB [3072][1024]
    unsigned short* wot   = (unsigned short*)(ws + (14L << 20));   // 2 MiB
    unsigned short* Qb    = (unsigned short*)(ws + (16L << 20));   // 8 MiB
    unsigned short* Kb    = (unsigned short*)(ws + (24L << 20));   // 8 MiB
    unsigned short* Vt    = (unsigned short*)(ws + (32L << 20));   // 8 MiB
    unsigned short* ctx   = (unsigned short*)(ws + (40L << 20));   // 8 MiB
    float* out = (float*)d_out;

    convert_kernel<<<2048, 256, 0, stream>>>(x, wq, wk, wv, wo, xb, wqkvt, wot);

    qkv_gemm_kernel<<<dim3(3 * DM / 128, MROWS / 128), 256, 0, stream>>>(
        xb, wqkvt, Qb, Kb, Vt);

    attn_kernel<<<dim3(NB * NH, 16), 512, 0, stream>>>(Qb, Kb, Vt, ctx);

    out_gemm_kernel<<<dim3(DM / 128, MROWS / 128), 256, 0, stream>>>(
        ctx, wot, bo, out);
}

// Round 13
// 186.615 us; speedup vs baseline: 1.1544x; 1.0216x over previous
//
#include <hip/hip_runtime.h>
#include <hip/hip_bf16.h>
#include <stdint.h>

#define NH 16
#define HDIM 64
#define NB 2
#define NSEQ 2048
#define DM 1024
#define MROWS (NB * NSEQ)   // 4096

typedef __attribute__((ext_vector_type(8))) short bf16x8;
typedef __attribute__((ext_vector_type(4))) float f32x4;

#define MFMA32(a, b, c) __builtin_amdgcn_mfma_f32_16x16x32_bf16(a, b, c, 0, 0, 0)

static __device__ __forceinline__ unsigned short f2bf(float f) {
    union { float f; unsigned u; } v;
    v.f = f;
    unsigned r = v.u + 0x7fffu + ((v.u >> 16) & 1u);   // RNE
    return (unsigned short)(r >> 16);
}

static __device__ __forceinline__ unsigned pack2bf(float a, float b) {
#if __has_builtin(__builtin_amdgcn_cvt_pk_bf16_f32)
    typedef __attribute__((ext_vector_type(2))) __bf16 bf2_t;
    union { bf2_t v; unsigned u; } c;
    c.v = __builtin_amdgcn_cvt_pk_bf16_f32(a, b);
    return c.u;
#else
    return (unsigned)f2bf(a) | ((unsigned)f2bf(b) << 16);
#endif
}

static __device__ __forceinline__ float fexp2(float x) {
#if __has_builtin(__builtin_amdgcn_exp2f)
    return __builtin_amdgcn_exp2f(x);
#else
    return exp2f(x);
#endif
}

typedef __attribute__((address_space(1))) void* gas_ptr;
typedef __attribute__((address_space(3))) void* las_ptr;

// async global->LDS, 16B per lane. LDS dest must be wave-uniform base + lane*16.
static __device__ __forceinline__ void load16_lds(const void* g, void* l) {
    __builtin_amdgcn_global_load_lds((gas_ptr)(uintptr_t)g, (las_ptr)(uintptr_t)l,
                                     16, 0, 0);
}

// ---------------------------------------------------------------------------
// Convert: x -> bf16 (blocks 0..1023), weights -> bf16 transposed via LDS
// tile transpose (blocks 1024..2047).
// ---------------------------------------------------------------------------
__global__ __launch_bounds__(256) void convert_kernel(
    const float* __restrict__ x,
    const float* __restrict__ wq, const float* __restrict__ wk,
    const float* __restrict__ wv, const float* __restrict__ wo,
    unsigned short* __restrict__ xb,
    unsigned short* __restrict__ wqkvt,
    unsigned short* __restrict__ wot)
{
    __shared__ unsigned short Ts[64][66];
    int t = threadIdx.x;
    int bx = blockIdx.x;
    if (bx < 1024) {
        const float4* xs = (const float4*)x + (long)bx * 1024;
        unsigned short* xd = xb + (long)bx * 4096;
#pragma unroll
        for (int i = 0; i < 4; i++) {
            float4 v = xs[i * 256 + t];
            ushort4 o;
            o.x = f2bf(v.x); o.y = f2bf(v.y); o.z = f2bf(v.z); o.w = f2bf(v.w);
            *(ushort4*)(xd + (i * 256 + t) * 4) = o;
        }
        return;
    }
    int wi = bx - 1024;
    int wsel = wi >> 8;                 // 0..3 = q,k,v,o
    int tile = wi & 255;
    int k0 = (tile >> 4) * 64, c0 = (tile & 15) * 64;
    const float* w = (wsel == 0) ? wq : (wsel == 1) ? wk : (wsel == 2) ? wv : wo;
    int lr = t >> 6, lc = t & 63;
#pragma unroll
    for (int rr = 0; rr < 16; rr++) {
        int row = rr * 4 + lr;
        Ts[row][lc] = f2bf(w[(long)(k0 + row) * DM + c0 + lc]);
    }
    __syncthreads();
    unsigned short* dst = (wsel == 3) ? wot : (wqkvt + (long)wsel * DM * DM);
#pragma unroll
    for (int rr = 0; rr < 16; rr++) {
        int crow = rr * 4 + lr;
        dst[(long)(c0 + crow) * DM + k0 + lc] = Ts[lc][crow];
    }
}

// ---------------------------------------------------------------------------
// m97-style 128x128 GEMM core with BANK-CONFLICT-FREE tile swizzle.
// LDS 16B-block b holds global block (row = b>>2, col = (b&3)^((row>>1)&3)).
// Fragment read offset: quad ^ ((l16>>1)&3) — lane-constant (rows accessed
// differ by multiples of 16). Per quarter-wave phase, banks are hit exactly
// 2x = free (was 8-way: row stride 64B gives row*16 mod 32 only 2 residues).
// ---------------------------------------------------------------------------
static __device__ __forceinline__ void gemm_tile_128(
    const unsigned short* __restrict__ A, const unsigned short* __restrict__ Bt,
    int m0, int n0, unsigned short* As, unsigned short* Bs, f32x4 (&acc)[4][4])
{
    int t = threadIdx.x;
    int lane = t & 63;
    int wave = t >> 6;
    int l16 = lane & 15, quad = lane >> 4;
    int wm = wave >> 1, wn = wave & 1;

    // staging source permutation (swizzled layout)
    int b0 = t, b1 = t + 256;
    int row0 = b0 >> 2, g0 = (b0 & 3) ^ ((row0 >> 1) & 3);
    int row1 = b1 >> 2, g1 = (b1 & 3) ^ ((row1 >> 1) & 3);
    const char* ga0 = (const char*)(A + (long)(m0 + row0) * DM) + g0 * 16;
    const char* ga1 = (const char*)(A + (long)(m0 + row1) * DM) + g1 * 16;
    const char* gb0 = (const char*)(Bt + (long)(n0 + row0) * DM) + g0 * 16;
    const char* gb1 = (const char*)(Bt + (long)(n0 + row1) * DM) + g1 * 16;
    char* sa0 = (char*)As + t * 16;
    char* sa1 = (char*)As + t * 16 + 4096;
    char* sb0 = (char*)Bs + t * 16;
    char* sb1 = (char*)Bs + t * 16 + 4096;

    int sread = quad ^ ((l16 >> 1) & 3);
    const unsigned short* fa = As + (wm * 64 + l16) * 32 + sread * 8;
    const unsigned short* fb = Bs + (wn * 64 + l16) * 32 + sread * 8;

    for (int kk = 0; kk < DM; kk += 32) {
        load16_lds(ga0 + kk * 2, sa0);
        load16_lds(ga1 + kk * 2, sa1);
        load16_lds(gb0 + kk * 2, sb0);
        load16_lds(gb1 + kk * 2, sb1);
        __syncthreads();
        bf16x8 af[4], bf[4];
#pragma unroll
        for (int r = 0; r < 4; r++) af[r] = *(const bf16x8*)(fa + r * 16 * 32);
#pragma unroll
        for (int c = 0; c < 4; c++) bf[c] = *(const bf16x8*)(fb + c * 16 * 32);
#pragma unroll
        for (int r = 0; r < 4; r++)
#pragma unroll
            for (int c = 0; c < 4; c++)
                acc[r][c] = MFMA32(af[r], bf[c], acc[r][c]);
        __syncthreads();
    }
}

// ---------------------------------------------------------------------------
// Fused QKV GEMM (epilogue unchanged from round 12).
// ---------------------------------------------------------------------------
__global__ __launch_bounds__(256) void qkv_gemm_kernel(
    const unsigned short* __restrict__ A,
    const unsigned short* __restrict__ Bt,
    unsigned short* __restrict__ Qo, unsigned short* __restrict__ Ko,
    unsigned short* __restrict__ Vt)
{
    __shared__ unsigned short As[128 * 32];
    __shared__ unsigned short Bs[128 * 32];
    __shared__ unsigned short Tw[4][16][72];

    f32x4 acc[4][4] = {};
    int m0 = blockIdx.y * 128, n0 = blockIdx.x * 128;
    gemm_tile_128(A, Bt, m0, n0, As, Bs, acc);

    int t = threadIdx.x, wave = t >> 6, lane = t & 63;
    int l16 = lane & 15, quad = lane >> 4;
    int wm = wave >> 1, wn = wave & 1;
    int rg0 = m0 + wm * 64;
    int cg0 = n0 + wn * 64;
    int z = cg0 >> 10;
    int b_ = rg0 >> 11;
    int nb0 = rg0 & (NSEQ - 1);
    int h = (cg0 & 1023) >> 6;
    long bh = (long)(b_ * NH + h);

    if (z < 2) {
        unsigned short* dst = (z == 0 ? Qo : Ko) + bh * NSEQ * HDIM;
#pragma unroll
        for (int r = 0; r < 4; r++)
#pragma unroll
            for (int reg = 0; reg < 4; reg++) {
                long rowb = (long)(nb0 + r * 16 + quad * 4 + reg) * HDIM;
#pragma unroll
                for (int c = 0; c < 4; c++)
                    dst[rowb + c * 16 + l16] = f2bf(acc[r][c][reg]);
            }
    } else {
        unsigned short* dst = Vt + bh * HDIM * NSEQ;
#pragma unroll
        for (int c = 0; c < 4; c++) {
#pragma unroll
            for (int r = 0; r < 4; r++) {
                ushort4 u;
                u.x = f2bf(acc[r][c][0]); u.y = f2bf(acc[r][c][1]);
                u.z = f2bf(acc[r][c][2]); u.w = f2bf(acc[r][c][3]);
                *(ushort4*)&Tw[wave][l16][r * 16 + quad * 4] = u;   // [hd][n]
            }
#pragma unroll
            for (int j = 0; j < 4; j++) {
                int lrow = j * 4 + quad;
                ushort4 u = *(const ushort4*)&Tw[wave][lrow][l16 * 4];
                *(ushort4*)(dst + (long)(c * 16 + lrow) * NSEQ + nb0 + l16 * 4) = u;
            }
        }
    }
}

// ---------------------------------------------------------------------------
// fixed-shift softmax; emits pb packing: key = (2p+(j>>2))*16 + quad*4 + (j&3)
// ---------------------------------------------------------------------------
static __device__ __forceinline__ void softmax_fixed(
    f32x4* s, bool mask, int qb, int kb, float sc2, float mrow,
    f32x4& l_vec, unsigned pbu[2][4], int l16, int quad)
{
    if (mask) {
        int fdm = qb + l16 - kb - quad * 4;   // key offset tt*16+r must be <= fdm
#pragma unroll
        for (int tt = 0; tt < 4; tt++)
#pragma unroll
            for (int r = 0; r < 4; r++)
                if (tt * 16 + r > fdm) s[tt][r] = -3e38f;
    }
    f32x4 e[4];
#pragma unroll
    for (int tt = 0; tt < 4; tt++)
#pragma unroll
        for (int r = 0; r < 4; r++)
            e[tt][r] = fexp2(s[tt][r] * sc2 - mrow);   // v_fma + v_exp
#pragma unroll
    for (int r = 0; r < 4; r++)
        l_vec[r] += (e[0][r] + e[1][r]) + (e[2][r] + e[3][r]);

#pragma unroll
    for (int p = 0; p < 2; p++) {
        pbu[p][0] = pack2bf(e[2 * p][0],     e[2 * p][1]);
        pbu[p][1] = pack2bf(e[2 * p][2],     e[2 * p][3]);
        pbu[p][2] = pack2bf(e[2 * p + 1][0], e[2 * p + 1][1]);
        pbu[p][3] = pack2bf(e[2 * p + 1][2], e[2 * p + 1][3]);
    }
}

// ---------------------------------------------------------------------------
// Flash attention v10 (unchanged from round 12): 512-thread blocks, one
// (t1,t0) pair each; waves 0-3 -> t1, 4-7 -> t0; shared double-buffered
// swizzled KV staging; grid (bh=32, pr=16) for XCD-L2 locality.
// ---------------------------------------------------------------------------
__global__ __launch_bounds__(512) void attn_kernel(
    const unsigned short* __restrict__ Q,
    const unsigned short* __restrict__ K,
    const unsigned short* __restrict__ Vt,
    unsigned short* __restrict__ ctx)
{
    __shared__ unsigned short KV[2][8192];         // [buf][K:4096 | V:4096]

    int t = threadIdx.x, w = t >> 6, lane = t & 63;
    int l16 = lane & 15, quad = lane >> 4;
    int r7 = l16 & 7;
    int bh = blockIdx.x;            // XCD = bh % 8 (L2 locality)
    int b_ = bh >> 4, h = bh & 15;
    int pr = blockIdx.y;            // pair id 0..15
    int t1 = 31 - pr, t0 = pr;
    int nch = t1 + 1;               // chunks staged by the block
    bool isT0 = (w >= 4);
    int myTile = isT0 ? t0 : t1;
    int myNch = myTile + 1;
    int qb = myTile * 64 + (w & 3) * 16;

    const unsigned short* Kg  = K  + (long)bh * NSEQ * HDIM;
    const unsigned short* Vtg = Vt + (long)bh * HDIM * NSEQ;

    const float log2e = 1.44269504f;
    float slope = exp2f(-0.5f * (float)(h + 1));
    float sc2 = 0.125f * log2e;     // scale * log2(e)
    float ss2 = slope * sc2;

    const unsigned short* qp = Q + ((long)bh * NSEQ + qb + l16) * HDIM + quad * 8;
    bf16x8 aq0 = *(const bf16x8*)qp;
    bf16x8 aq1 = *(const bf16x8*)(qp + 32);

    // alibi C-init (chunk-constant): cinit[tt][r] = slope*(tt*16+quad*4+r)
    f32x4 cinit[4];
#pragma unroll
    for (int tt = 0; tt < 4; tt++)
#pragma unroll
        for (int r = 0; r < 4; r++)
            cinit[tt][r] = slope * (float)(tt * 16 + quad * 4 + r);

    f32x4 lv = {};
    f32x4 o[4] = {};

    // staging: 512 threads x 16B cover K (8KB) and V (8KB) in one pass each
    int row = t >> 3, sp = t & 7, sw = sp ^ (row & 7);
    const unsigned short* gk = Kg + row * HDIM + sw * 8;
    const unsigned short* gv = Vtg + (long)row * NSEQ + sw * 8;

    {   // stage chunk 0
        unsigned short* buf = KV[0];
        load16_lds(gk, buf + t * 8);
        load16_lds(gv, buf + 4096 + t * 8);
    }

    for (int c = 0; c < nch; c++) {
        __syncthreads();
        if (c + 1 < nch) {
            int kb2 = (c + 1) * 64;
            unsigned short* buf = KV[(c + 1) & 1];
            load16_lds(gk + kb2 * HDIM, buf + t * 8);
            load16_lds(gv + kb2, buf + 4096 + t * 8);
        }
        if (isT0 && c >= myNch) continue;   // wave-uniform idle (barrier-safe)

        const unsigned short* Ks = KV[c & 1];
        const unsigned short* Vs = KV[c & 1] + 4096;
        int kb = c * 64;

        // ---- S^T = K·Q^T + alibi (one 16-q slice per wave)
        f32x4 s[4];
#pragma unroll
        for (int tt = 0; tt < 4; tt++) {
            int rr = tt * 16 + l16;
            bf16x8 k0 = *(const bf16x8*)(Ks + (rr * 8 + (quad ^ r7)) * 8);
            bf16x8 k1 = *(const bf16x8*)(Ks + (rr * 8 + ((quad + 4) ^ r7)) * 8);
            f32x4 z = MFMA32(k0, aq0, cinit[tt]);
            s[tt] = MFMA32(k1, aq1, z);
        }

        float mrow = ss2 * (float)(qb + l16 - kb);
        unsigned pb[2][4];
        softmax_fixed(s, c == myNch - 1, qb, kb, sc2, mrow, lv, pb, l16, quad);

        // ---- O^T += V^T·P^T (round-6/8/9/11 verified pattern)
        int q2 = quad >> 1, q1b = (quad & 1) << 3;
#pragma unroll
        for (int cb = 0; cb < 4; cb++) {
            int rd = cb * 16 + l16;
            const char* vrow = (const char*)(Vs + rd * 64);
            int x7 = rd & 7;
#pragma unroll
            for (int p = 0; p < 2; p++) {
                union { bf16x8 v; uint2 u2[2]; } a;
                int sb0 = 4 * p + q2;
                int sb1 = 4 * p + 2 + q2;
                a.u2[0] = *(const uint2*)(vrow + ((sb0 ^ x7) << 4) + q1b);
                a.u2[1] = *(const uint2*)(vrow + ((sb1 ^ x7) << 4) + q1b);
                union { unsigned u[4]; bf16x8 v; } bv;
#pragma unroll
                for (int i = 0; i < 4; i++) bv.u[i] = pb[p][i];
                o[cb] = MFMA32(a.v, bv.v, o[cb]);
            }
        }
    }

    // ---- final l reduction + normalize, store ctx [b, n=q, h, d]
    {
        float lt = (lv[0] + lv[1]) + (lv[2] + lv[3]);
        lt += __shfl_xor(lt, 16);
        lt += __shfl_xor(lt, 32);
        float inv = 1.0f / lt;
        long base = (((long)b_ * NSEQ + (qb + l16)) * NH + h) * HDIM + quad * 4;
#pragma unroll
        for (int cb = 0; cb < 4; cb++) {
            uint2 u;
            u.x = pack2bf(o[cb][0] * inv, o[cb][1] * inv);
            u.y = pack2bf(o[cb][2] * inv, o[cb][3] * inv);
            *(uint2*)(ctx + base + cb * 16) = u;
        }
    }
}

// ---------------------------------------------------------------------------
// Output projection (swizzled core via gemm_tile_128).
// ---------------------------------------------------------------------------
__global__ __launch_bounds__(256) void out_gemm_kernel(
    const unsigned short* __restrict__ A,
    const unsigned short* __restrict__ Bt,
    const float* __restrict__ bias,
    float* __restrict__ out)
{
    __shared__ unsigned short As[128 * 32];
    __shared__ unsigned short Bs[128 * 32];
    f32x4 acc[4][4] = {};
    int m0 = blockIdx.y * 128, n0 = blockIdx.x * 128;
    gemm_tile_128(A, Bt, m0, n0, As, Bs, acc);

    int t = threadIdx.x, wave = t >> 6, lane = t & 63;
    int l16 = lane & 15, quad = lane >> 4;
    int wm = wave >> 1, wn = wave & 1;
    int rg0 = m0 + wm * 64, cg0 = n0 + wn * 64;
#pragma unroll
    for (int c = 0; c < 4; c++) {
        float bc = bias[cg0 + c * 16 + l16];
#pragma unroll
        for (int r = 0; r < 4; r++)
#pragma unroll
            for (int reg = 0; reg < 4; reg++)
                out[(long)(rg0 + r * 16 + quad * 4 + reg) * DM + cg0 + c * 16 + l16] =
                    acc[r][c][reg] + bc;
    }
}

// ---------------------------------------------------------------------------
extern "C" void kernel_launch(void* const* d_in, const int* in_sizes, int n_in,
                              void* d_out, int out_size, void* d_ws, size_t ws_size,
                              hipStream_t stream)
{
    const float* x  = (const float*)d_in[0];
    const float* wq = (const float*)d_in[1];
    const float* wk = (const float*)d_in[2];
    const float* wv = (const float*)d_in[3];
    const float* wo = (const float*)d_in[4];
    const float* bo = (const float*)d_in[5];

    char* ws = (char*)d_ws;
    unsigned short* xb    = (unsigned short*)(ws);                 // 8 MiB
    unsigned short* wqkvt = (unsigned short*)(ws + (8L  << 20));   // 6 MiB [3072][1024]
    unsigned short* wot   = (unsigned short*)(ws + (14L << 20));   // 2 MiB
    unsigned short* Qb    = (unsigned short*)(ws + (16L << 20));   // 8 MiB
    unsigned short* Kb    = (unsigned short*)(ws + (24L << 20));   // 8 MiB
    unsigned short* Vt    = (unsigned short*)(ws + (32L << 20));   // 8 MiB
    unsigned short* ctx   = (unsigned short*)(ws + (40L << 20));   // 8 MiB
    float* out = (float*)d_out;

    convert_kernel<<<2048, 256, 0, stream>>>(x, wq, wk, wv, wo, xb, wqkvt, wot);

    qkv_gemm_kernel<<<dim3(3 * DM / 128, MROWS / 128), 256, 0, stream>>>(
        xb, wqkvt, Qb, Kb, Vt);

    attn_kernel<<<dim3(NB * NH, 16), 512, 0, stream>>>(Qb, Kb, Vt, ctx);

    out_gemm_kernel<<<dim3(DM / 128, MROWS / 128), 256, 0, stream>>>(
        ctx, wot, bo, out);
}

// Round 14
// 182.150 us; speedup vs baseline: 1.1827x; 1.0245x over previous
//
#include <hip/hip_runtime.h>
#include <hip/hip_bf16.h>
#include <stdint.h>

#define NH 16
#define HDIM 64
#define NB 2
#define NSEQ 2048
#define DM 1024
#define MROWS (NB * NSEQ)   // 4096

typedef __attribute__((ext_vector_type(8))) short bf16x8;
typedef __attribute__((ext_vector_type(4))) float f32x4;

#define MFMA32(a, b, c) __builtin_amdgcn_mfma_f32_16x16x32_bf16(a, b, c, 0, 0, 0)

static __device__ __forceinline__ unsigned short f2bf(float f) {
    union { float f; unsigned u; } v;
    v.f = f;
    unsigned r = v.u + 0x7fffu + ((v.u >> 16) & 1u);   // RNE
    return (unsigned short)(r >> 16);
}

static __device__ __forceinline__ unsigned pack2bf(float a, float b) {
#if __has_builtin(__builtin_amdgcn_cvt_pk_bf16_f32)
    typedef __attribute__((ext_vector_type(2))) __bf16 bf2_t;
    union { bf2_t v; unsigned u; } c;
    c.v = __builtin_amdgcn_cvt_pk_bf16_f32(a, b);
    return c.u;
#else
    return (unsigned)f2bf(a) | ((unsigned)f2bf(b) << 16);
#endif
}

static __device__ __forceinline__ float fexp2(float x) {
#if __has_builtin(__builtin_amdgcn_exp2f)
    return __builtin_amdgcn_exp2f(x);
#else
    return exp2f(x);
#endif
}

typedef __attribute__((address_space(1))) void* gas_ptr;
typedef __attribute__((address_space(3))) void* las_ptr;

// async global->LDS, 16B per lane. LDS dest must be wave-uniform base + lane*16.
static __device__ __forceinline__ void load16_lds(const void* g, void* l) {
    __builtin_amdgcn_global_load_lds((gas_ptr)(uintptr_t)g, (las_ptr)(uintptr_t)l,
                                     16, 0, 0);
}

// ---------------------------------------------------------------------------
// Convert: x -> bf16 (blocks 0..1023), weights -> bf16 transposed via LDS
// tile transpose (blocks 1024..2047). (unchanged)
// ---------------------------------------------------------------------------
__global__ __launch_bounds__(256) void convert_kernel(
    const float* __restrict__ x,
    const float* __restrict__ wq, const float* __restrict__ wk,
    const float* __restrict__ wv, const float* __restrict__ wo,
    unsigned short* __restrict__ xb,
    unsigned short* __restrict__ wqkvt,
    unsigned short* __restrict__ wot)
{
    __shared__ unsigned short Ts[64][66];
    int t = threadIdx.x;
    int bx = blockIdx.x;
    if (bx < 1024) {
        const float4* xs = (const float4*)x + (long)bx * 1024;
        unsigned short* xd = xb + (long)bx * 4096;
#pragma unroll
        for (int i = 0; i < 4; i++) {
            float4 v = xs[i * 256 + t];
            ushort4 o;
            o.x = f2bf(v.x); o.y = f2bf(v.y); o.z = f2bf(v.z); o.w = f2bf(v.w);
            *(ushort4*)(xd + (i * 256 + t) * 4) = o;
        }
        return;
    }
    int wi = bx - 1024;
    int wsel = wi >> 8;                 // 0..3 = q,k,v,o
    int tile = wi & 255;
    int k0 = (tile >> 4) * 64, c0 = (tile & 15) * 64;
    const float* w = (wsel == 0) ? wq : (wsel == 1) ? wk : (wsel == 2) ? wv : wo;
    int lr = t >> 6, lc = t & 63;
#pragma unroll
    for (int rr = 0; rr < 16; rr++) {
        int row = rr * 4 + lr;
        Ts[row][lc] = f2bf(w[(long)(k0 + row) * DM + c0 + lc]);
    }
    __syncthreads();
    unsigned short* dst = (wsel == 3) ? wot : (wqkvt + (long)wsel * DM * DM);
#pragma unroll
    for (int rr = 0; rr < 16; rr++) {
        int crow = rr * 4 + lr;
        dst[(long)(c0 + crow) * DM + k0 + lc] = Ts[lc][crow];
    }
}

// ---------------------------------------------------------------------------
// 64x128 (MxN) GEMM core, bank-conflict-free swizzle (round-13 verified
// XOR pattern — lane-constant since wm*32 and r*16 vanish mod 4 after >>1).
// 256 threads = 4 waves in 2x2; wave tile 32x64 = 2x4 MFMA frags.
// Per K-iter: A 4KB (1 load16/thread) + B 8KB (2) staged; 8 MFMA, 6 b128.
// Grid doubles vs 128x128 -> 4 blocks/CU (qkv) / 2 (out) for drain overlap.
// ---------------------------------------------------------------------------
static __device__ __forceinline__ void gemm_tile_64x128(
    const unsigned short* __restrict__ A, const unsigned short* __restrict__ Bt,
    int m0, int n0, unsigned short* As, unsigned short* Bs, f32x4 (&acc)[2][4])
{
    int t = threadIdx.x;
    int lane = t & 63;
    int wave = t >> 6;
    int l16 = lane & 15, quad = lane >> 4;
    int wm = wave >> 1, wn = wave & 1;

    // staging source permutation (swizzled layout): block b -> row b>>2,
    // col (b&3)^((row>>1)&3)
    int b0 = t, b1 = t + 256;
    int rowA = b0 >> 2, gA = (b0 & 3) ^ ((rowA >> 1) & 3);
    int rowB0 = b0 >> 2, gB0 = gA;
    int rowB1 = b1 >> 2, gB1 = (b1 & 3) ^ ((rowB1 >> 1) & 3);
    const char* ga  = (const char*)(A  + (long)(m0 + rowA)  * DM) + gA  * 16;
    const char* gb0 = (const char*)(Bt + (long)(n0 + rowB0) * DM) + gB0 * 16;
    const char* gb1 = (const char*)(Bt + (long)(n0 + rowB1) * DM) + gB1 * 16;
    char* sa  = (char*)As + t * 16;
    char* sb0 = (char*)Bs + t * 16;
    char* sb1 = (char*)Bs + t * 16 + 4096;

    int sread = quad ^ ((l16 >> 1) & 3);
    const unsigned short* fa = As + (wm * 32 + l16) * 32 + sread * 8;
    const unsigned short* fb = Bs + (wn * 64 + l16) * 32 + sread * 8;

    for (int kk = 0; kk < DM; kk += 32) {
        load16_lds(ga + kk * 2, sa);
        load16_lds(gb0 + kk * 2, sb0);
        load16_lds(gb1 + kk * 2, sb1);
        __syncthreads();
        bf16x8 af[2], bf[4];
#pragma unroll
        for (int r = 0; r < 2; r++) af[r] = *(const bf16x8*)(fa + r * 16 * 32);
#pragma unroll
        for (int c = 0; c < 4; c++) bf[c] = *(const bf16x8*)(fb + c * 16 * 32);
#pragma unroll
        for (int r = 0; r < 2; r++)
#pragma unroll
            for (int c = 0; c < 4; c++)
                acc[r][c] = MFMA32(af[r], bf[c], acc[r][c]);
        __syncthreads();
    }
}

// ---------------------------------------------------------------------------
// Fused QKV GEMM, 64x128 tiles. Q,K -> [bh][n][hd]; V -> [bh][hd][n] via
// per-wave LDS transpose (32-row slab, ushort2 coalesced stores).
// ---------------------------------------------------------------------------
__global__ __launch_bounds__(256) void qkv_gemm_kernel(
    const unsigned short* __restrict__ A,
    const unsigned short* __restrict__ Bt,
    unsigned short* __restrict__ Qo, unsigned short* __restrict__ Ko,
    unsigned short* __restrict__ Vt)
{
    __shared__ unsigned short As[64 * 32];
    __shared__ unsigned short Bs[128 * 32];
    __shared__ unsigned short Tw[4][16][40];

    f32x4 acc[2][4] = {};
    int m0 = blockIdx.y * 64, n0 = blockIdx.x * 128;
    gemm_tile_64x128(A, Bt, m0, n0, As, Bs, acc);

    int t = threadIdx.x, wave = t >> 6, lane = t & 63;
    int l16 = lane & 15, quad = lane >> 4;
    int wm = wave >> 1, wn = wave & 1;
    int rg0 = m0 + wm * 32;
    int cg0 = n0 + wn * 64;
    int z = cg0 >> 10;
    int b_ = rg0 >> 11;
    int nb0 = rg0 & (NSEQ - 1);
    int h = (cg0 & 1023) >> 6;
    long bh = (long)(b_ * NH + h);

    if (z < 2) {
        unsigned short* dst = (z == 0 ? Qo : Ko) + bh * NSEQ * HDIM;
#pragma unroll
        for (int r = 0; r < 2; r++)
#pragma unroll
            for (int reg = 0; reg < 4; reg++) {
                long rowb = (long)(nb0 + r * 16 + quad * 4 + reg) * HDIM;
#pragma unroll
                for (int c = 0; c < 4; c++)
                    dst[rowb + c * 16 + l16] = f2bf(acc[r][c][reg]);
            }
    } else {
        // V: values are V[n = nb0 + r*16+quad*4+reg][hd = c*16+l16].
        // Transpose 32n x 16hd slab per c through Tw, store [hd][n].
        unsigned short* dst = Vt + bh * HDIM * NSEQ;
#pragma unroll
        for (int c = 0; c < 4; c++) {
#pragma unroll
            for (int r = 0; r < 2; r++) {
                ushort4 u;
                u.x = f2bf(acc[r][c][0]); u.y = f2bf(acc[r][c][1]);
                u.z = f2bf(acc[r][c][2]); u.w = f2bf(acc[r][c][3]);
                *(ushort4*)&Tw[wave][l16][r * 16 + quad * 4] = u;   // [hd][n 0..31]
            }
#pragma unroll
            for (int j = 0; j < 4; j++) {
                int lrow = j * 4 + quad;                  // hd row 0..15
                ushort2 u = *(const ushort2*)&Tw[wave][lrow][l16 * 2];
                *(ushort2*)(dst + (long)(c * 16 + lrow) * NSEQ + nb0 + l16 * 2) = u;
            }
        }
    }
}

// ---------------------------------------------------------------------------
// fixed-shift softmax; emits pb packing: key = (2p+(j>>2))*16 + quad*4 + (j&3)
// ---------------------------------------------------------------------------
static __device__ __forceinline__ void softmax_fixed(
    f32x4* s, bool mask, int qb, int kb, float sc2, float mrow,
    f32x4& l_vec, unsigned pbu[2][4], int l16, int quad)
{
    if (mask) {
        int fdm = qb + l16 - kb - quad * 4;   // key offset tt*16+r must be <= fdm
#pragma unroll
        for (int tt = 0; tt < 4; tt++)
#pragma unroll
            for (int r = 0; r < 4; r++)
                if (tt * 16 + r > fdm) s[tt][r] = -3e38f;
    }
    f32x4 e[4];
#pragma unroll
    for (int tt = 0; tt < 4; tt++)
#pragma unroll
        for (int r = 0; r < 4; r++)
            e[tt][r] = fexp2(s[tt][r] * sc2 - mrow);   // v_fma + v_exp
#pragma unroll
    for (int r = 0; r < 4; r++)
        l_vec[r] += (e[0][r] + e[1][r]) + (e[2][r] + e[3][r]);

#pragma unroll
    for (int p = 0; p < 2; p++) {
        pbu[p][0] = pack2bf(e[2 * p][0],     e[2 * p][1]);
        pbu[p][1] = pack2bf(e[2 * p][2],     e[2 * p][3]);
        pbu[p][2] = pack2bf(e[2 * p + 1][0], e[2 * p + 1][1]);
        pbu[p][3] = pack2bf(e[2 * p + 1][2], e[2 * p + 1][3]);
    }
}

// ---------------------------------------------------------------------------
// Flash attention v10 (unchanged from rounds 12/13): 512-thread blocks, one
// (t1,t0) pair each; waves 0-3 -> t1, 4-7 -> t0; shared double-buffered
// swizzled KV staging; grid (bh=32, pr=16) for XCD-L2 locality.
// ---------------------------------------------------------------------------
__global__ __launch_bounds__(512) void attn_kernel(
    const unsigned short* __restrict__ Q,
    const unsigned short* __restrict__ K,
    const unsigned short* __restrict__ Vt,
    unsigned short* __restrict__ ctx)
{
    __shared__ unsigned short KV[2][8192];         // [buf][K:4096 | V:4096]

    int t = threadIdx.x, w = t >> 6, lane = t & 63;
    int l16 = lane & 15, quad = lane >> 4;
    int r7 = l16 & 7;
    int bh = blockIdx.x;            // XCD = bh % 8 (L2 locality)
    int b_ = bh >> 4, h = bh & 15;
    int pr = blockIdx.y;            // pair id 0..15
    int t1 = 31 - pr, t0 = pr;
    int nch = t1 + 1;               // chunks staged by the block
    bool isT0 = (w >= 4);
    int myTile = isT0 ? t0 : t1;
    int myNch = myTile + 1;
    int qb = myTile * 64 + (w & 3) * 16;

    const unsigned short* Kg  = K  + (long)bh * NSEQ * HDIM;
    const unsigned short* Vtg = Vt + (long)bh * HDIM * NSEQ;

    const float log2e = 1.44269504f;
    float slope = exp2f(-0.5f * (float)(h + 1));
    float sc2 = 0.125f * log2e;     // scale * log2(e)
    float ss2 = slope * sc2;

    const unsigned short* qp = Q + ((long)bh * NSEQ + qb + l16) * HDIM + quad * 8;
    bf16x8 aq0 = *(const bf16x8*)qp;
    bf16x8 aq1 = *(const bf16x8*)(qp + 32);

    // alibi C-init (chunk-constant): cinit[tt][r] = slope*(tt*16+quad*4+r)
    f32x4 cinit[4];
#pragma unroll
    for (int tt = 0; tt < 4; tt++)
#pragma unroll
        for (int r = 0; r < 4; r++)
            cinit[tt][r] = slope * (float)(tt * 16 + quad * 4 + r);

    f32x4 lv = {};
    f32x4 o[4] = {};

    // staging: 512 threads x 16B cover K (8KB) and V (8KB) in one pass each
    int row = t >> 3, sp = t & 7, sw = sp ^ (row & 7);
    const unsigned short* gk = Kg + row * HDIM + sw * 8;
    const unsigned short* gv = Vtg + (long)row * NSEQ + sw * 8;

    {   // stage chunk 0
        unsigned short* buf = KV[0];
        load16_lds(gk, buf + t * 8);
        load16_lds(gv, buf + 4096 + t * 8);
    }

    for (int c = 0; c < nch; c++) {
        __syncthreads();
        if (c + 1 < nch) {
            int kb2 = (c + 1) * 64;
            unsigned short* buf = KV[(c + 1) & 1];
            load16_lds(gk + kb2 * HDIM, buf + t * 8);
            load16_lds(gv + kb2, buf + 4096 + t * 8);
        }
        if (isT0 && c >= myNch) continue;   // wave-uniform idle (barrier-safe)

        const unsigned short* Ks = KV[c & 1];
        const unsigned short* Vs = KV[c & 1] + 4096;
        int kb = c * 64;

        // ---- S^T = K·Q^T + alibi (one 16-q slice per wave)
        f32x4 s[4];
#pragma unroll
        for (int tt = 0; tt < 4; tt++) {
            int rr = tt * 16 + l16;
            bf16x8 k0 = *(const bf16x8*)(Ks + (rr * 8 + (quad ^ r7)) * 8);
            bf16x8 k1 = *(const bf16x8*)(Ks + (rr * 8 + ((quad + 4) ^ r7)) * 8);
            f32x4 z = MFMA32(k0, aq0, cinit[tt]);
            s[tt] = MFMA32(k1, aq1, z);
        }

        float mrow = ss2 * (float)(qb + l16 - kb);
        unsigned pb[2][4];
        softmax_fixed(s, c == myNch - 1, qb, kb, sc2, mrow, lv, pb, l16, quad);

        // ---- O^T += V^T·P^T (verified pattern)
        int q2 = quad >> 1, q1b = (quad & 1) << 3;
#pragma unroll
        for (int cb = 0; cb < 4; cb++) {
            int rd = cb * 16 + l16;
            const char* vrow = (const char*)(Vs + rd * 64);
            int x7 = rd & 7;
#pragma unroll
            for (int p = 0; p < 2; p++) {
                union { bf16x8 v; uint2 u2[2]; } a;
                int sb0 = 4 * p + q2;
                int sb1 = 4 * p + 2 + q2;
                a.u2[0] = *(const uint2*)(vrow + ((sb0 ^ x7) << 4) + q1b);
                a.u2[1] = *(const uint2*)(vrow + ((sb1 ^ x7) << 4) + q1b);
                union { unsigned u[4]; bf16x8 v; } bv;
#pragma unroll
                for (int i = 0; i < 4; i++) bv.u[i] = pb[p][i];
                o[cb] = MFMA32(a.v, bv.v, o[cb]);
            }
        }
    }

    // ---- final l reduction + normalize, store ctx [b, n=q, h, d]
    {
        float lt = (lv[0] + lv[1]) + (lv[2] + lv[3]);
        lt += __shfl_xor(lt, 16);
        lt += __shfl_xor(lt, 32);
        float inv = 1.0f / lt;
        long base = (((long)b_ * NSEQ + (qb + l16)) * NH + h) * HDIM + quad * 4;
#pragma unroll
        for (int cb = 0; cb < 4; cb++) {
            uint2 u;
            u.x = pack2bf(o[cb][0] * inv, o[cb][1] * inv);
            u.y = pack2bf(o[cb][2] * inv, o[cb][3] * inv);
            *(uint2*)(ctx + base + cb * 16) = u;
        }
    }
}

// ---------------------------------------------------------------------------
// Output projection, 64x128 tiles (grid 512 = 2 blocks/CU, was 1).
// ---------------------------------------------------------------------------
__global__ __launch_bounds__(256) void out_gemm_kernel(
    const unsigned short* __restrict__ A,
    const unsigned short* __restrict__ Bt,
    const float* __restrict__ bias,
    float* __restrict__ out)
{
    __shared__ unsigned short As[64 * 32];
    __shared__ unsigned short Bs[128 * 32];
    f32x4 acc[2][4] = {};
    int m0 = blockIdx.y * 64, n0 = blockIdx.x * 128;
    gemm_tile_64x128(A, Bt, m0, n0, As, Bs, acc);

    int t = threadIdx.x, wave = t >> 6, lane = t & 63;
    int l16 = lane & 15, quad = lane >> 4;
    int wm = wave >> 1, wn = wave & 1;
    int rg0 = m0 + wm * 32, cg0 = n0 + wn * 64;
#pragma unroll
    for (int c = 0; c < 4; c++) {
        float bc = bias[cg0 + c * 16 + l16];
#pragma unroll
        for (int r = 0; r < 2; r++)
#pragma unroll
            for (int reg = 0; reg < 4; reg++)
                out[(long)(rg0 + r * 16 + quad * 4 + reg) * DM + cg0 + c * 16 + l16] =
                    acc[r][c][reg] + bc;
    }
}

// ---------------------------------------------------------------------------
extern "C" void kernel_launch(void* const* d_in, const int* in_sizes, int n_in,
                              void* d_out, int out_size, void* d_ws, size_t ws_size,
                              hipStream_t stream)
{
    const float* x  = (const float*)d_in[0];
    const float* wq = (const float*)d_in[1];
    const float* wk = (const float*)d_in[2];
    const float* wv = (const float*)d_in[3];
    const float* wo = (const float*)d_in[4];
    const float* bo = (const float*)d_in[5];

    char* ws = (char*)d_ws;
    unsigned short* xb    = (unsigned short*)(ws);                 // 8 MiB
    unsigned short* wqkvt = (unsigned short*)(ws + (8L  << 20));   // 6 MiB [3072][1024]
    unsigned short* wot   = (unsigned short*)(ws + (14L << 20));   // 2 MiB
    unsigned short* Qb    = (unsigned short*)(ws + (16L << 20));   // 8 MiB
    unsigned short* Kb    = (unsigned short*)(ws + (24L << 20));   // 8 MiB
    unsigned short* Vt    = (unsigned short*)(ws + (32L << 20));   // 8 MiB
    unsigned short* ctx   = (unsigned short*)(ws + (40L << 20));   // 8 MiB
    float* out = (float*)d_out;

    convert_kernel<<<2048, 256, 0, stream>>>(x, wq, wk, wv, wo, xb, wqkvt, wot);

    qkv_gemm_kernel<<<dim3(3 * DM / 128, MROWS / 64), 256, 0, stream>>>(
        xb, wqkvt, Qb, Kb, Vt);

    attn_kernel<<<dim3(NB * NH, 16), 512, 0, stream>>>(Qb, Kb, Vt, ctx);

    out_gemm_kernel<<<dim3(DM / 128, MROWS / 64), 256, 0, stream>>>(
        ctx, wot, bo, out);
}

// Round 15
// 173.516 us; speedup vs baseline: 1.2416x; 1.0498x over previous
//
#include <hip/hip_runtime.h>
#include <hip/hip_bf16.h>
#include <stdint.h>

#define NH 16
#define HDIM 64
#define NB 2
#define NSEQ 2048
#define DM 1024
#define MROWS (NB * NSEQ)   // 4096

typedef __attribute__((ext_vector_type(8))) short bf16x8;
typedef __attribute__((ext_vector_type(4))) float f32x4;

#define MFMA32(a, b, c) __builtin_amdgcn_mfma_f32_16x16x32_bf16(a, b, c, 0, 0, 0)

static __device__ __forceinline__ unsigned short f2bf(float f) {
    union { float f; unsigned u; } v;
    v.f = f;
    unsigned r = v.u + 0x7fffu + ((v.u >> 16) & 1u);   // RNE
    return (unsigned short)(r >> 16);
}

static __device__ __forceinline__ unsigned pack2bf(float a, float b) {
#if __has_builtin(__builtin_amdgcn_cvt_pk_bf16_f32)
    typedef __attribute__((ext_vector_type(2))) __bf16 bf2_t;
    union { bf2_t v; unsigned u; } c;
    c.v = __builtin_amdgcn_cvt_pk_bf16_f32(a, b);
    return c.u;
#else
    return (unsigned)f2bf(a) | ((unsigned)f2bf(b) << 16);
#endif
}

static __device__ __forceinline__ float fexp2(float x) {
#if __has_builtin(__builtin_amdgcn_exp2f)
    return __builtin_amdgcn_exp2f(x);
#else
    return exp2f(x);
#endif
}

typedef __attribute__((address_space(1))) void* gas_ptr;
typedef __attribute__((address_space(3))) void* las_ptr;

// async global->LDS, 16B per lane. LDS dest must be wave-uniform base + lane*16.
static __device__ __forceinline__ void load16_lds(const void* g, void* l) {
    __builtin_amdgcn_global_load_lds((gas_ptr)(uintptr_t)g, (las_ptr)(uintptr_t)l,
                                     16, 0, 0);
}

// ---------------------------------------------------------------------------
// Convert: x -> bf16 (blocks 0..1023), weights -> bf16 transposed via LDS
// tile transpose (blocks 1024..2047). (unchanged)
// ---------------------------------------------------------------------------
__global__ __launch_bounds__(256) void convert_kernel(
    const float* __restrict__ x,
    const float* __restrict__ wq, const float* __restrict__ wk,
    const float* __restrict__ wv, const float* __restrict__ wo,
    unsigned short* __restrict__ xb,
    unsigned short* __restrict__ wqkvt,
    unsigned short* __restrict__ wot)
{
    __shared__ unsigned short Ts[64][66];
    int t = threadIdx.x;
    int bx = blockIdx.x;
    if (bx < 1024) {
        const float4* xs = (const float4*)x + (long)bx * 1024;
        unsigned short* xd = xb + (long)bx * 4096;
#pragma unroll
        for (int i = 0; i < 4; i++) {
            float4 v = xs[i * 256 + t];
            ushort4 o;
            o.x = f2bf(v.x); o.y = f2bf(v.y); o.z = f2bf(v.z); o.w = f2bf(v.w);
            *(ushort4*)(xd + (i * 256 + t) * 4) = o;
        }
        return;
    }
    int wi = bx - 1024;
    int wsel = wi >> 8;                 // 0..3 = q,k,v,o
    int tile = wi & 255;
    int k0 = (tile >> 4) * 64, c0 = (tile & 15) * 64;
    const float* w = (wsel == 0) ? wq : (wsel == 1) ? wk : (wsel == 2) ? wv : wo;
    int lr = t >> 6, lc = t & 63;
#pragma unroll
    for (int rr = 0; rr < 16; rr++) {
        int row = rr * 4 + lr;
        Ts[row][lc] = f2bf(w[(long)(k0 + row) * DM + c0 + lc]);
    }
    __syncthreads();
    unsigned short* dst = (wsel == 3) ? wot : (wqkvt + (long)wsel * DM * DM);
#pragma unroll
    for (int rr = 0; rr < 16; rr++) {
        int crow = rr * 4 + lr;
        dst[(long)(c0 + crow) * DM + k0 + lc] = Ts[lc][crow];
    }
}

// ---------------------------------------------------------------------------
// DOUBLE-BUFFERED GEMM core (attn-proven staging pattern applied to GEMM).
// MR = 16-row MFMA frags per wave (4 -> 128xN tile, 2 -> 64xN tile).
// One barrier per K-iter: stage(k+1) issues right after the barrier that
// releases compute(k) -> staging latency overlaps compute. Round-13
// bank-conflict-free swizzle kept (block b -> row b>>2, col (b&3)^((row>>1)&3);
// read offset quad^((l16>>1)&3), lane-constant).
// Hazards: WAR on buffer reuse ordered by intervening barrier; vmcnt(0) at
// each barrier guarantees stage(k) landed before compute(k).
// ---------------------------------------------------------------------------
template<int MR>
static __device__ __forceinline__ void gemm_core_db(
    const unsigned short* __restrict__ A,
    const unsigned short* __restrict__ Bt,
    int m0, int n0,
    unsigned short* __restrict__ As,   // [2][MR*32*32] shorts
    unsigned short* __restrict__ Bs,   // [2][128*32] shorts
    f32x4 (&acc)[MR][4])
{
    constexpr int MT  = MR * 32;       // M tile rows
    constexpr int ASZ = MT * 32;       // shorts per A buffer
    constexpr int BSZ = 128 * 32;      // shorts per B buffer
    constexpr int NA  = MT / 64;       // A load16 per thread (2 or 1)

    int t = threadIdx.x;
    int lane = t & 63;
    int wave = t >> 6;
    int l16 = lane & 15, quad = lane >> 4;
    int wm = wave >> 1, wn = wave & 1;

    const char* gA[NA];
#pragma unroll
    for (int i = 0; i < NA; i++) {
        int b = i * 256 + t;
        int row = b >> 2, g = (b & 3) ^ ((row >> 1) & 3);
        gA[i] = (const char*)(A + (long)(m0 + row) * DM) + g * 16;
    }
    const char* gB[2];
#pragma unroll
    for (int i = 0; i < 2; i++) {
        int b = i * 256 + t;
        int row = b >> 2, g = (b & 3) ^ ((row >> 1) & 3);
        gB[i] = (const char*)(Bt + (long)(n0 + row) * DM) + g * 16;
    }

    int sread = quad ^ ((l16 >> 1) & 3);
    int faOff = (wm * (MT / 2) + l16) * 32 + sread * 8;
    int fbOff = (wn * 64 + l16) * 32 + sread * 8;

    // stage k=0 into buffer 0
#pragma unroll
    for (int i = 0; i < NA; i++)
        load16_lds(gA[i], (char*)As + i * 4096 + t * 16);
#pragma unroll
    for (int i = 0; i < 2; i++)
        load16_lds(gB[i], (char*)Bs + i * 4096 + t * 16);

    for (int kk = 0; kk < DM; kk += 32) {
        int cur = (kk >> 5) & 1;
        __syncthreads();                       // stage(kk) landed; buf free
        if (kk + 32 < DM) {
            int nxt = cur ^ 1;
            char* abuf = (char*)(As + nxt * ASZ);
            char* bbuf = (char*)(Bs + nxt * BSZ);
#pragma unroll
            for (int i = 0; i < NA; i++)
                load16_lds(gA[i] + (kk + 32) * 2, abuf + i * 4096 + t * 16);
#pragma unroll
            for (int i = 0; i < 2; i++)
                load16_lds(gB[i] + (kk + 32) * 2, bbuf + i * 4096 + t * 16);
        }
        const unsigned short* fa = As + cur * ASZ + faOff;
        const unsigned short* fb = Bs + cur * BSZ + fbOff;
        bf16x8 af[MR], bf[4];
#pragma unroll
        for (int r = 0; r < MR; r++) af[r] = *(const bf16x8*)(fa + r * 16 * 32);
#pragma unroll
        for (int c = 0; c < 4; c++) bf[c] = *(const bf16x8*)(fb + c * 16 * 32);
#pragma unroll
        for (int r = 0; r < MR; r++)
#pragma unroll
            for (int c = 0; c < 4; c++)
                acc[r][c] = MFMA32(af[r], bf[c], acc[r][c]);
    }
}

// ---------------------------------------------------------------------------
// Fused QKV GEMM, 128x128 tile, double-buffered core. Epilogue = round-13
// verified (Q,K -> [bh][n][hd]; V -> [bh][hd][n] via per-wave Tw transpose).
// ---------------------------------------------------------------------------
__global__ __launch_bounds__(256) void qkv_gemm_kernel(
    const unsigned short* __restrict__ A,
    const unsigned short* __restrict__ Bt,
    unsigned short* __restrict__ Qo, unsigned short* __restrict__ Ko,
    unsigned short* __restrict__ Vt)
{
    __shared__ unsigned short As[2][128 * 32];
    __shared__ unsigned short Bs[2][128 * 32];
    __shared__ unsigned short Tw[4][16][72];

    f32x4 acc[4][4] = {};
    int m0 = blockIdx.y * 128, n0 = blockIdx.x * 128;
    gemm_core_db<4>(A, Bt, m0, n0, &As[0][0], &Bs[0][0], acc);

    int t = threadIdx.x, wave = t >> 6, lane = t & 63;
    int l16 = lane & 15, quad = lane >> 4;
    int wm = wave >> 1, wn = wave & 1;
    int rg0 = m0 + wm * 64;
    int cg0 = n0 + wn * 64;
    int z = cg0 >> 10;
    int b_ = rg0 >> 11;
    int nb0 = rg0 & (NSEQ - 1);
    int h = (cg0 & 1023) >> 6;
    long bh = (long)(b_ * NH + h);

    if (z < 2) {
        unsigned short* dst = (z == 0 ? Qo : Ko) + bh * NSEQ * HDIM;
#pragma unroll
        for (int r = 0; r < 4; r++)
#pragma unroll
            for (int reg = 0; reg < 4; reg++) {
                long rowb = (long)(nb0 + r * 16 + quad * 4 + reg) * HDIM;
#pragma unroll
                for (int c = 0; c < 4; c++)
                    dst[rowb + c * 16 + l16] = f2bf(acc[r][c][reg]);
            }
    } else {
        unsigned short* dst = Vt + bh * HDIM * NSEQ;
#pragma unroll
        for (int c = 0; c < 4; c++) {
#pragma unroll
            for (int r = 0; r < 4; r++) {
                ushort4 u;
                u.x = f2bf(acc[r][c][0]); u.y = f2bf(acc[r][c][1]);
                u.z = f2bf(acc[r][c][2]); u.w = f2bf(acc[r][c][3]);
                *(ushort4*)&Tw[wave][l16][r * 16 + quad * 4] = u;   // [hd][n]
            }
#pragma unroll
            for (int j = 0; j < 4; j++) {
                int lrow = j * 4 + quad;
                ushort4 u = *(const ushort4*)&Tw[wave][lrow][l16 * 4];
                *(ushort4*)(dst + (long)(c * 16 + lrow) * NSEQ + nb0 + l16 * 4) = u;
            }
        }
    }
}

// ---------------------------------------------------------------------------
// fixed-shift softmax; emits pb packing: key = (2p+(j>>2))*16 + quad*4 + (j&3)
// ---------------------------------------------------------------------------
static __device__ __forceinline__ void softmax_fixed(
    f32x4* s, bool mask, int qb, int kb, float sc2, float mrow,
    f32x4& l_vec, unsigned pbu[2][4], int l16, int quad)
{
    if (mask) {
        int fdm = qb + l16 - kb - quad * 4;   // key offset tt*16+r must be <= fdm
#pragma unroll
        for (int tt = 0; tt < 4; tt++)
#pragma unroll
            for (int r = 0; r < 4; r++)
                if (tt * 16 + r > fdm) s[tt][r] = -3e38f;
    }
    f32x4 e[4];
#pragma unroll
    for (int tt = 0; tt < 4; tt++)
#pragma unroll
        for (int r = 0; r < 4; r++)
            e[tt][r] = fexp2(s[tt][r] * sc2 - mrow);   // v_fma + v_exp
#pragma unroll
    for (int r = 0; r < 4; r++)
        l_vec[r] += (e[0][r] + e[1][r]) + (e[2][r] + e[3][r]);

#pragma unroll
    for (int p = 0; p < 2; p++) {
        pbu[p][0] = pack2bf(e[2 * p][0],     e[2 * p][1]);
        pbu[p][1] = pack2bf(e[2 * p][2],     e[2 * p][3]);
        pbu[p][2] = pack2bf(e[2 * p + 1][0], e[2 * p + 1][1]);
        pbu[p][3] = pack2bf(e[2 * p + 1][2], e[2 * p + 1][3]);
    }
}

// ---------------------------------------------------------------------------
// Flash attention v10 (unchanged from rounds 12-14): 512-thread blocks, one
// (t1,t0) pair each; waves 0-3 -> t1, 4-7 -> t0; shared double-buffered
// swizzled KV staging; grid (bh=32, pr=16) for XCD-L2 locality.
// ---------------------------------------------------------------------------
__global__ __launch_bounds__(512) void attn_kernel(
    const unsigned short* __restrict__ Q,
    const unsigned short* __restrict__ K,
    const unsigned short* __restrict__ Vt,
    unsigned short* __restrict__ ctx)
{
    __shared__ unsigned short KV[2][8192];         // [buf][K:4096 | V:4096]

    int t = threadIdx.x, w = t >> 6, lane = t & 63;
    int l16 = lane & 15, quad = lane >> 4;
    int r7 = l16 & 7;
    int bh = blockIdx.x;            // XCD = bh % 8 (L2 locality)
    int b_ = bh >> 4, h = bh & 15;
    int pr = blockIdx.y;            // pair id 0..15
    int t1 = 31 - pr, t0 = pr;
    int nch = t1 + 1;               // chunks staged by the block
    bool isT0 = (w >= 4);
    int myTile = isT0 ? t0 : t1;
    int myNch = myTile + 1;
    int qb = myTile * 64 + (w & 3) * 16;

    const unsigned short* Kg  = K  + (long)bh * NSEQ * HDIM;
    const unsigned short* Vtg = Vt + (long)bh * HDIM * NSEQ;

    const float log2e = 1.44269504f;
    float slope = exp2f(-0.5f * (float)(h + 1));
    float sc2 = 0.125f * log2e;     // scale * log2(e)
    float ss2 = slope * sc2;

    const unsigned short* qp = Q + ((long)bh * NSEQ + qb + l16) * HDIM + quad * 8;
    bf16x8 aq0 = *(const bf16x8*)qp;
    bf16x8 aq1 = *(const bf16x8*)(qp + 32);

    // alibi C-init (chunk-constant): cinit[tt][r] = slope*(tt*16+quad*4+r)
    f32x4 cinit[4];
#pragma unroll
    for (int tt = 0; tt < 4; tt++)
#pragma unroll
        for (int r = 0; r < 4; r++)
            cinit[tt][r] = slope * (float)(tt * 16 + quad * 4 + r);

    f32x4 lv = {};
    f32x4 o[4] = {};

    // staging: 512 threads x 16B cover K (8KB) and V (8KB) in one pass each
    int row = t >> 3, sp = t & 7, sw = sp ^ (row & 7);
    const unsigned short* gk = Kg + row * HDIM + sw * 8;
    const unsigned short* gv = Vtg + (long)row * NSEQ + sw * 8;

    {   // stage chunk 0
        unsigned short* buf = KV[0];
        load16_lds(gk, buf + t * 8);
        load16_lds(gv, buf + 4096 + t * 8);
    }

    for (int c = 0; c < nch; c++) {
        __syncthreads();
        if (c + 1 < nch) {
            int kb2 = (c + 1) * 64;
            unsigned short* buf = KV[(c + 1) & 1];
            load16_lds(gk + kb2 * HDIM, buf + t * 8);
            load16_lds(gv + kb2, buf + 4096 + t * 8);
        }
        if (isT0 && c >= myNch) continue;   // wave-uniform idle (barrier-safe)

        const unsigned short* Ks = KV[c & 1];
        const unsigned short* Vs = KV[c & 1] + 4096;
        int kb = c * 64;

        // ---- S^T = K·Q^T + alibi (one 16-q slice per wave)
        f32x4 s[4];
#pragma unroll
        for (int tt = 0; tt < 4; tt++) {
            int rr = tt * 16 + l16;
            bf16x8 k0 = *(const bf16x8*)(Ks + (rr * 8 + (quad ^ r7)) * 8);
            bf16x8 k1 = *(const bf16x8*)(Ks + (rr * 8 + ((quad + 4) ^ r7)) * 8);
            f32x4 z = MFMA32(k0, aq0, cinit[tt]);
            s[tt] = MFMA32(k1, aq1, z);
        }

        float mrow = ss2 * (float)(qb + l16 - kb);
        unsigned pb[2][4];
        softmax_fixed(s, c == myNch - 1, qb, kb, sc2, mrow, lv, pb, l16, quad);

        // ---- O^T += V^T·P^T (verified pattern)
        int q2 = quad >> 1, q1b = (quad & 1) << 3;
#pragma unroll
        for (int cb = 0; cb < 4; cb++) {
            int rd = cb * 16 + l16;
            const char* vrow = (const char*)(Vs + rd * 64);
            int x7 = rd & 7;
#pragma unroll
            for (int p = 0; p < 2; p++) {
                union { bf16x8 v; uint2 u2[2]; } a;
                int sb0 = 4 * p + q2;
                int sb1 = 4 * p + 2 + q2;
                a.u2[0] = *(const uint2*)(vrow + ((sb0 ^ x7) << 4) + q1b);
                a.u2[1] = *(const uint2*)(vrow + ((sb1 ^ x7) << 4) + q1b);
                union { unsigned u[4]; bf16x8 v; } bv;
#pragma unroll
                for (int i = 0; i < 4; i++) bv.u[i] = pb[p][i];
                o[cb] = MFMA32(a.v, bv.v, o[cb]);
            }
        }
    }

    // ---- final l reduction + normalize, store ctx [b, n=q, h, d]
    {
        float lt = (lv[0] + lv[1]) + (lv[2] + lv[3]);
        lt += __shfl_xor(lt, 16);
        lt += __shfl_xor(lt, 32);
        float inv = 1.0f / lt;
        long base = (((long)b_ * NSEQ + (qb + l16)) * NH + h) * HDIM + quad * 4;
#pragma unroll
        for (int cb = 0; cb < 4; cb++) {
            uint2 u;
            u.x = pack2bf(o[cb][0] * inv, o[cb][1] * inv);
            u.y = pack2bf(o[cb][2] * inv, o[cb][3] * inv);
            *(uint2*)(ctx + base + cb * 16) = u;
        }
    }
}

// ---------------------------------------------------------------------------
// Output projection, 64x128 tile, double-buffered core (512 blocks = 2/CU).
// ---------------------------------------------------------------------------
__global__ __launch_bounds__(256) void out_gemm_kernel(
    const unsigned short* __restrict__ A,
    const unsigned short* __restrict__ Bt,
    const float* __restrict__ bias,
    float* __restrict__ out)
{
    __shared__ unsigned short As[2][64 * 32];
    __shared__ unsigned short Bs[2][128 * 32];
    f32x4 acc[2][4] = {};
    int m0 = blockIdx.y * 64, n0 = blockIdx.x * 128;
    gemm_core_db<2>(A, Bt, m0, n0, &As[0][0], &Bs[0][0], acc);

    int t = threadIdx.x, wave = t >> 6, lane = t & 63;
    int l16 = lane & 15, quad = lane >> 4;
    int wm = wave >> 1, wn = wave & 1;
    int rg0 = m0 + wm * 32, cg0 = n0 + wn * 64;
#pragma unroll
    for (int c = 0; c < 4; c++) {
        float bc = bias[cg0 + c * 16 + l16];
#pragma unroll
        for (int r = 0; r < 2; r++)
#pragma unroll
            for (int reg = 0; reg < 4; reg++)
                out[(long)(rg0 + r * 16 + quad * 4 + reg) * DM + cg0 + c * 16 + l16] =
                    acc[r][c][reg] + bc;
    }
}

// ---------------------------------------------------------------------------
extern "C" void kernel_launch(void* const* d_in, const int* in_sizes, int n_in,
                              void* d_out, int out_size, void* d_ws, size_t ws_size,
                              hipStream_t stream)
{
    const float* x  = (const float*)d_in[0];
    const float* wq = (const float*)d_in[1];
    const float* wk = (const float*)d_in[2];
    const float* wv = (const float*)d_in[3];
    const float* wo = (const float*)d_in[4];
    const float* bo = (const float*)d_in[5];

    char* ws = (char*)d_ws;
    unsigned short* xb    = (unsigned short*)(ws);                 // 8 MiB
    unsigned short* wqkvt = (unsigned short*)(ws + (8L  << 20));   // 6 MiB [3072][1024]
    unsigned short* wot   = (unsigned short*)(ws + (14L << 20));   // 2 MiB
    unsigned short* Qb    = (unsigned short*)(ws + (16L << 20));   // 8 MiB
    unsigned short* Kb    = (unsigned short*)(ws + (24L << 20));   // 8 MiB
    unsigned short* Vt    = (unsigned short*)(ws + (32L << 20));   // 8 MiB
    unsigned short* ctx   = (unsigned short*)(ws + (40L << 20));   // 8 MiB
    float* out = (float*)d_out;

    convert_kernel<<<2048, 256, 0, stream>>>(x, wq, wk, wv, wo, xb, wqkvt, wot);

    qkv_gemm_kernel<<<dim3(3 * DM / 128, MROWS / 128), 256, 0, stream>>>(
        xb, wqkvt, Qb, Kb, Vt);

    attn_kernel<<<dim3(NB * NH, 16), 512, 0, stream>>>(Qb, Kb, Vt, ctx);

    out_gemm_kernel<<<dim3(DM / 128, MROWS / 64), 256, 0, stream>>>(
        ctx, wot, bo, out);
}